// Round 6
// baseline (540.004 us; speedup 1.0000x reference)
//
#include <hip/hip_runtime.h>
#include <math.h>
#include <float.h>
#include <stdint.h>

#define B_ 4
#define N_ 8192
#define K_ 9
#define NPTS (B_ * N_)           // 32768
#define NROWS (NPTS * K_)        // 294912
#define SPLIT 8
#define CHUNK (N_ / SPLIT)       // 1024
#define NGROUP 16
#define GSIZE (CHUNK / NGROUP)   // 64
#define PT_BLOCKS (NPTS / 64)    // 512
#define ROW_BLOCKS (NROWS / 256) // 1152

// Distance: EXACT source shape of rounds 1-4 (passed). Plain mul/add tree —
// clang's fp-contract forms the same fma pattern for this tree in every
// kernel (contraction is per-expression, context-free), so k_knn2 and
// k_merge produce bit-identical distances. DO NOT rewrite with explicit
// fmaf / reassociate: round 5 did (reversed accumulation order) and flipped
// a knife-edge 9th/10th-neighbor decision vs the reference.
__device__ __forceinline__ float dist2f(float4 q, float4 c) {
  float dot = q.x * c.x + q.y * c.y + q.z * c.z;
  return (q.w + c.w) - 2.0f * dot;
}

// ---------------- K0: pack x (B,N,3) -> float4 (x,y,z,|x|^2) -------------------
__launch_bounds__(256)
__global__ void k_pack(const float* __restrict__ x, float4* __restrict__ P) {
  int i = blockIdx.x * 256 + threadIdx.x;
  if (i >= NPTS) return;
  float a = x[3 * i], b = x[3 * i + 1], c = x[3 * i + 2];
  P[i] = make_float4(a, b, c, a * a + b * b + c * c);
}

// ---------------- K1: two-level exact top-9 per 1024-chunk ----------------------
// All per-lane state in NAMED SCALARS (promote-alloca drops arrays -> scratch).
#define GDECL(G) float gd##G; int gi##G;
#define SCANG(G)                                                           \
  { float bgd = FLT_MAX; int bgi = 0; int jg = j0 + G * GSIZE;             \
    _Pragma("clang loop unroll(disable)")                                  \
    for (int jj = 0; jj < GSIZE; jj += 4) {                                \
      int j = jg + jj;                                                     \
      float4 c0 = Pb[j], c1 = Pb[j + 1], c2 = Pb[j + 2], c3 = Pb[j + 3];   \
      float d0 = dist2f(q, c0), d1 = dist2f(q, c1);                        \
      float d2 = dist2f(q, c2), d3 = dist2f(q, c3);                        \
      d0 = (j + 0 == n) ? FLT_MAX : d0;                                    \
      d1 = (j + 1 == n) ? FLT_MAX : d1;                                    \
      d2 = (j + 2 == n) ? FLT_MAX : d2;                                    \
      d3 = (j + 3 == n) ? FLT_MAX : d3;                                    \
      bool l0 = d0 < bgd; bgd = l0 ? d0 : bgd; bgi = l0 ? (j + 0) : bgi;   \
      bool l1 = d1 < bgd; bgd = l1 ? d1 : bgd; bgi = l1 ? (j + 1) : bgi;   \
      bool l2 = d2 < bgd; bgd = l2 ? d2 : bgd; bgi = l2 ? (j + 2) : bgi;   \
      bool l3 = d3 < bgd; bgd = l3 ? d3 : bgd; bgi = l3 ? (j + 3) : bgi;   \
    }                                                                      \
    gd##G = bgd; gi##G = bgi; }
#define LM(G)                                                              \
  { bool lt = (gd##G < wd) | ((gd##G == wd) & (gi##G < wi));               \
    wd = lt ? gd##G : wd; wi = lt ? gi##G : wi; wg = lt ? G : wg; }
#define WBK(G)                                                             \
  { bool m = (wg == G); gd##G = m ? nd : gd##G; gi##G = m ? ni : gi##G; }

__launch_bounds__(64, 4)
__global__ void k_knn2(const float4* __restrict__ P, int* __restrict__ PBI) {
  int pt_blk = blockIdx.x >> 3;          // / SPLIT
  int s = blockIdx.x & (SPLIT - 1);
  int p = pt_blk * 64 + threadIdx.x;
  int b = p >> 13;
  int n = p & (N_ - 1);
  const float4* __restrict__ Pb = P + b * N_;
  float4 q = Pb[n];
  int j0 = s * CHUNK;

  GDECL(0) GDECL(1) GDECL(2) GDECL(3) GDECL(4) GDECL(5) GDECL(6) GDECL(7)
  GDECL(8) GDECL(9) GDECL(10) GDECL(11) GDECL(12) GDECL(13) GDECL(14) GDECL(15)

  SCANG(0) SCANG(1) SCANG(2) SCANG(3) SCANG(4) SCANG(5) SCANG(6) SCANG(7)
  SCANG(8) SCANG(9) SCANG(10) SCANG(11) SCANG(12) SCANG(13) SCANG(14) SCANG(15)

#pragma clang loop unroll(disable)
  for (int r = 0; r < K_; ++r) {
    // lexicographic min over the 16 records
    float wd = gd0; int wi = gi0; int wg = 0;
    LM(1) LM(2) LM(3) LM(4) LM(5) LM(6) LM(7)
    LM(8) LM(9) LM(10) LM(11) LM(12) LM(13) LM(14) LM(15)
    PBI[(size_t)(s * K_ + r) * NPTS + p] = wi;   // coalesced across lanes

    // refill winning group: lex-min over keys strictly > (wd, wi)
    int base = j0 + wg * GSIZE;
    float nd = FLT_MAX; int ni = 0;
#pragma clang loop unroll(disable)
    for (int jj = 0; jj < GSIZE; jj += 4) {
      int j = base + jj;
      float4 c0 = Pb[j], c1 = Pb[j + 1], c2 = Pb[j + 2], c3 = Pb[j + 3];
      float d0 = dist2f(q, c0), d1 = dist2f(q, c1);
      float d2 = dist2f(q, c2), d3 = dist2f(q, c3);
      d0 = (j + 0 == n) ? FLT_MAX : d0;
      d1 = (j + 1 == n) ? FLT_MAX : d1;
      d2 = (j + 2 == n) ? FLT_MAX : d2;
      d3 = (j + 3 == n) ? FLT_MAX : d3;
      bool k0 = (d0 > wd) | ((d0 == wd) & ((j + 0) > wi));
      bool k1 = (d1 > wd) | ((d1 == wd) & ((j + 1) > wi));
      bool k2 = (d2 > wd) | ((d2 == wd) & ((j + 2) > wi));
      bool k3 = (d3 > wd) | ((d3 == wd) & ((j + 3) > wi));
      d0 = k0 ? d0 : FLT_MAX;
      d1 = k1 ? d1 : FLT_MAX;
      d2 = k2 ? d2 : FLT_MAX;
      d3 = k3 ? d3 : FLT_MAX;
      bool l0 = d0 < nd; nd = l0 ? d0 : nd; ni = l0 ? (j + 0) : ni;
      bool l1 = d1 < nd; nd = l1 ? d1 : nd; ni = l1 ? (j + 1) : ni;
      bool l2 = d2 < nd; nd = l2 ? d2 : nd; ni = l2 ? (j + 2) : ni;
      bool l3 = d3 < nd; nd = l3 ? d3 : nd; ni = l3 ? (j + 3) : ni;
    }
    WBK(0) WBK(1) WBK(2) WBK(3) WBK(4) WBK(5) WBK(6) WBK(7)
    WBK(8) WBK(9) WBK(10) WBK(11) WBK(12) WBK(13) WBK(14) WBK(15)
  }
}

// Register-resident sorted top-9 insert (named scalars).
#define LVL(bdv, biv)                                                     \
  { bool lt = cd < (bdv); float td = (bdv); int ti = (biv);               \
    (bdv) = lt ? cd : (bdv); (biv) = lt ? ci : (biv);                     \
    cd = lt ? td : cd; ci = lt ? ti : ci; }
#define INS9ALL()                                                         \
  LVL(b0d, b0i) LVL(b1d, b1i) LVL(b2d, b2i) LVL(b3d, b3i) LVL(b4d, b4i)  \
  LVL(b5d, b5i) LVL(b6d, b6i) LVL(b7d, b7i) LVL(b8d, b8i)
#define TOP9_DECL()                                                       \
  float b0d = FLT_MAX, b1d = FLT_MAX, b2d = FLT_MAX, b3d = FLT_MAX,       \
        b4d = FLT_MAX, b5d = FLT_MAX, b6d = FLT_MAX, b7d = FLT_MAX,       \
        b8d = FLT_MAX;                                                    \
  int b0i = 0, b1i = 0, b2i = 0, b3i = 0, b4i = 0, b5i = 0, b6i = 0,      \
      b7i = 0, b8i = 0;

#define MKREL(T)                                                          \
  float rx##T, ry##T, rz##T, ph##T;                                       \
  { float4 m = Pb[b##T##i];                                               \
    rx##T = m.x - q.x; ry##T = m.y - q.y; rz##T = m.z - q.z;              \
    ph##T = atan2f(ry##T, rx##T); }

#define CE(A, Bv)                                                         \
  { bool lt = ph##Bv < ph##A; float t0;                                   \
    t0 = ph##A; ph##A = lt ? ph##Bv : t0; ph##Bv = lt ? t0 : ph##Bv;      \
    t0 = rx##A; rx##A = lt ? rx##Bv : t0; rx##Bv = lt ? t0 : rx##Bv;      \
    t0 = ry##A; ry##A = lt ? ry##Bv : t0; ry##Bv = lt ? t0 : ry##Bv;      \
    t0 = rz##A; rz##A = lt ? rz##Bv : t0; rz##Bv = lt ? t0 : rz##Bv; }

#define STREL(T)                                                          \
  { REL[(size_t)(0 * K_ + T) * NPTS + p] = rx##T;                         \
    REL[(size_t)(1 * K_ + T) * NPTS + p] = ry##T;                         \
    REL[(size_t)(2 * K_ + T) * NPTS + p] = rz##T; }

// ---------------- K2: merge 8 sorted index lists, phi-sort, sign ---------------
__launch_bounds__(64)
__global__ void k_merge(const float4* __restrict__ P, const int* __restrict__ PBI,
                        float* __restrict__ REL, float* __restrict__ SGN) {
  int p = blockIdx.x * 64 + threadIdx.x;
  int b = p >> 13;
  int n = p & (N_ - 1);
  const float4* __restrict__ Pb = P + b * N_;
  float4 q = Pb[n];

  // Process slices in ascending (s, rank) order; within each sorted list keys
  // ascend; ties across lists resolve to earlier chunk (= smaller index).
  // Strict-< insertion => exact top_k tie-breaking. dist2f is bit-identical
  // to k_knn2's (same expression tree).
  TOP9_DECL();
#pragma unroll 8
  for (int t = 0; t < SPLIT * K_; ++t) {
    int ci = PBI[(size_t)t * NPTS + p];         // coalesced
    float4 c = Pb[ci];
    float cd = dist2f(q, c);
    INS9ALL();
  }

  MKREL(0) MKREL(1) MKREL(2) MKREL(3) MKREL(4)
  MKREL(5) MKREL(6) MKREL(7) MKREL(8)

  // stable insertion-sort network ascending by phi (36 strict-< CEs)
  CE(0,1)
  CE(1,2) CE(0,1)
  CE(2,3) CE(1,2) CE(0,1)
  CE(3,4) CE(2,3) CE(1,2) CE(0,1)
  CE(4,5) CE(3,4) CE(2,3) CE(1,2) CE(0,1)
  CE(5,6) CE(4,5) CE(3,4) CE(2,3) CE(1,2) CE(0,1)
  CE(6,7) CE(5,6) CE(4,5) CE(3,4) CE(2,3) CE(1,2) CE(0,1)
  CE(7,8) CE(6,7) CE(5,6) CE(4,5) CE(3,4) CE(2,3) CE(1,2) CE(0,1)

  // sign from triangle 0's NORMALIZED nx, exactly as rounds 1-4 / reference
  float nx0 = ry0 * rz1 - rz0 * ry1;
  float ny0 = rz0 * rx1 - rx0 * rz1;
  float nz0 = rx0 * ry1 - ry0 * rx1;
  float nrm0 = sqrtf(nx0 * nx0 + ny0 * ny0 + nz0 * nz0) + 1e-6f;
  SGN[p] = ((nx0 / nrm0) > 0.0f) ? 1.0f : -1.0f;

  STREL(0) STREL(1) STREL(2) STREL(3) STREL(4)
  STREL(5) STREL(6) STREL(7) STREL(8)
}

// ---------------- K3: per-row features + @W1+b1 -> H1 (chan-major) + stats -----
__launch_bounds__(256)
__global__ void k_featrow(const float* __restrict__ REL, const float* __restrict__ SGN,
                          const float* __restrict__ W1, const float* __restrict__ b1,
                          float* __restrict__ H1, double* __restrict__ part1) {
  int r = blockIdx.x * 256 + threadIdx.x;   // row id = t*NPTS + p
  int t = r >> 15;                          // / NPTS
  int p = r & (NPTS - 1);
  int t2 = (t + 1 == K_) ? 0 : t + 1;

  float v1x = REL[(size_t)(0 * K_ + t) * NPTS + p];
  float v1y = REL[(size_t)(1 * K_ + t) * NPTS + p];
  float v1z = REL[(size_t)(2 * K_ + t) * NPTS + p];
  float v2x = REL[(size_t)(0 * K_ + t2) * NPTS + p];
  float v2y = REL[(size_t)(1 * K_ + t2) * NPTS + p];
  float v2z = REL[(size_t)(2 * K_ + t2) * NPTS + p];
  float sgn = SGN[p];

  float cx = 0.5f * (v1x + v2x);
  float cy = 0.5f * (v1y + v2y);
  float cz = 0.5f * (v1z + v2z);
  float nx = v1y * v2z - v1z * v2y;
  float ny = v1z * v2x - v1x * v2z;
  float nz = v1x * v2y - v1y * v2x;
  float nrm = sqrtf(nx * nx + ny * ny + nz * nz) + 1e-6f;
  nx /= nrm; ny /= nrm; nz /= nrm;
  nx *= sgn; ny *= sgn; nz *= sgn;
  float pos = (nx * cx + ny * cy + nz * cz) / 1.7320508075688772f;

  float fv[7] = {cx, cy, cz, nx, ny, nz, pos};
  float o[10];
#pragma unroll
  for (int c = 0; c < 10; ++c) {
    float h = b1[c];
#pragma unroll
    for (int rr = 0; rr < 7; ++rr) h = fmaf(fv[rr], W1[rr * 10 + c], h);
    o[c] = h;
    H1[(size_t)c * NROWS + r] = h;          // coalesced
  }

  __shared__ double sred[4][20];
  int lane = threadIdx.x & 63, wv = threadIdx.x >> 6;
#pragma unroll
  for (int c = 0; c < 10; ++c) {
    double a = (double)o[c];
#pragma unroll
    for (int off = 32; off > 0; off >>= 1) a += __shfl_down(a, off);
    if (lane == 0) sred[wv][c] = a;
    double qq = (double)o[c] * (double)o[c];
#pragma unroll
    for (int off = 32; off > 0; off >>= 1) qq += __shfl_down(qq, off);
    if (lane == 0) sred[wv][10 + c] = qq;
  }
  __syncthreads();
  if (threadIdx.x < 20) {
    part1[(size_t)blockIdx.x * 20 + threadIdx.x] =
        sred[0][threadIdx.x] + sred[1][threadIdx.x] +
        sred[2][threadIdx.x] + sred[3][threadIdx.x];
  }
}

// ---------------- K4: reduce partials -> mu[10], rsqrt(var+eps)[10] -------------
__launch_bounds__(256)
__global__ void k_reduce(const double* __restrict__ part, int nblk,
                         float* __restrict__ MR) {
  __shared__ double acc[256];
  int tid = threadIdx.x;
  int c = tid % 20;
  int ch = tid / 20;
  double s = 0.0;
  if (ch < 12) {
    for (int i = ch; i < nblk; i += 12) s += part[(size_t)i * 20 + c];
  }
  acc[tid] = s;
  __syncthreads();
  if (tid < 20) {
    double t = 0.0;
#pragma unroll
    for (int k2 = 0; k2 < 12; ++k2) t += acc[k2 * 20 + tid];
    acc[tid] = t;
  }
  __syncthreads();
  if (tid < 10) {
    double mu = acc[tid] / (double)NROWS;
    double var = acc[10 + tid] / (double)NROWS - mu * mu;
    MR[tid] = (float)mu;
    MR[10 + tid] = (float)(1.0 / sqrt(var + 1e-5));
  }
}

// ---------------- K5: bn1 + relu + @W2+b2 -> H2 (chan-major) + stats ------------
__launch_bounds__(256)
__global__ void k_mlp2(const float* __restrict__ H1, const float* __restrict__ MR1,
                       const float* __restrict__ g1, const float* __restrict__ be1,
                       const float* __restrict__ W2, const float* __restrict__ b2,
                       float* __restrict__ H2, double* __restrict__ part2) {
  int r = blockIdx.x * 256 + threadIdx.x;
  float v[10];
#pragma unroll
  for (int c = 0; c < 10; ++c) {
    float h = H1[(size_t)c * NROWS + r];
    float z = g1[c] * (h - MR1[c]) * MR1[10 + c] + be1[c];
    v[c] = z > 0.0f ? z : 0.0f;
  }
  float o[10];
#pragma unroll
  for (int c = 0; c < 10; ++c) {
    float h = b2[c];
#pragma unroll
    for (int t = 0; t < 10; ++t) h = fmaf(v[t], W2[t * 10 + c], h);
    o[c] = h;
    H2[(size_t)c * NROWS + r] = h;
  }

  __shared__ double sred[4][20];
  int lane = threadIdx.x & 63, wv = threadIdx.x >> 6;
#pragma unroll
  for (int c = 0; c < 10; ++c) {
    double a = (double)o[c];
#pragma unroll
    for (int off = 32; off > 0; off >>= 1) a += __shfl_down(a, off);
    if (lane == 0) sred[wv][c] = a;
    double qq = (double)o[c] * (double)o[c];
#pragma unroll
    for (int off = 32; off > 0; off >>= 1) qq += __shfl_down(qq, off);
    if (lane == 0) sred[wv][10 + c] = qq;
  }
  __syncthreads();
  if (threadIdx.x < 20) {
    part2[(size_t)blockIdx.x * 20 + threadIdx.x] =
        sred[0][threadIdx.x] + sred[1][threadIdx.x] +
        sred[2][threadIdx.x] + sred[3][threadIdx.x];
  }
}

// ---------------- K6: bn2 + relu + max over k -> out ----------------------------
__launch_bounds__(256)
__global__ void k_out(const float* __restrict__ H2, const float* __restrict__ MR2,
                      const float* __restrict__ g2, const float* __restrict__ be2,
                      float* __restrict__ out) {
  int p = blockIdx.x * 256 + threadIdx.x;
  if (p >= NPTS) return;
#pragma unroll
  for (int c = 0; c < 10; ++c) {
    float m = -FLT_MAX;
#pragma unroll
    for (int j = 0; j < K_; ++j) {
      float h = H2[(size_t)c * NROWS + j * NPTS + p];   // coalesced
      float z = g2[c] * (h - MR2[c]) * MR2[10 + c] + be2[c];
      z = z > 0.0f ? z : 0.0f;
      m = fmaxf(m, z);
    }
    out[(size_t)p * 10 + c] = m;
  }
}

extern "C" void kernel_launch(void* const* d_in, const int* in_sizes, int n_in,
                              void* d_out, int out_size, void* d_ws, size_t ws_size,
                              hipStream_t stream) {
  (void)in_sizes; (void)n_in; (void)out_size; (void)ws_size;
  const float* x  = (const float*)d_in[0];
  const float* W1 = (const float*)d_in[1];
  const float* b1 = (const float*)d_in[2];
  const float* g1 = (const float*)d_in[3];
  const float* be1= (const float*)d_in[4];
  const float* W2 = (const float*)d_in[5];
  const float* b2 = (const float*)d_in[6];
  const float* g2 = (const float*)d_in[7];
  const float* be2= (const float*)d_in[8];
  float* out = (float*)d_out;

  char* base = (char*)d_ws;
  float4* P   = (float4*)base;                                  // 512 KB
  int*    PBI = (int*)(base + (size_t)NPTS * 16);               // 72 slices, 9.44 MB
  float*  REL = (float*)((char*)PBI + (size_t)SPLIT * K_ * NPTS * 4);  // 27 slices, 3.54 MB
  float*  SGN = REL + (size_t)3 * K_ * NPTS;                    // 128 KB
  float*  H1  = SGN + NPTS;                                     // 11.8 MB
  double* part1 = (double*)(H1 + (size_t)10 * NROWS);           // 1152*20 dbl, 184 KB
  float*  MR1 = (float*)(part1 + (size_t)ROW_BLOCKS * 20);
  float*  MR2 = MR1 + 32;
  // H2 aliases the PBI+REL region (dead after k_merge / k_featrow respectively)
  float*  H2 = (float*)PBI;                                     // 11.8 MB
  double* part2 = (double*)((char*)PBI + (size_t)10 * NROWS * 4);  // inside PBI+REL

  k_pack<<<(NPTS + 255) / 256, 256, 0, stream>>>(x, P);
  k_knn2<<<PT_BLOCKS * SPLIT, 64, 0, stream>>>(P, PBI);
  k_merge<<<PT_BLOCKS, 64, 0, stream>>>(P, PBI, REL, SGN);
  k_featrow<<<ROW_BLOCKS, 256, 0, stream>>>(REL, SGN, W1, b1, H1, part1);
  k_reduce<<<1, 256, 0, stream>>>(part1, ROW_BLOCKS, MR1);
  k_mlp2<<<ROW_BLOCKS, 256, 0, stream>>>(H1, MR1, g1, be1, W2, b2, H2, part2);
  k_reduce<<<1, 256, 0, stream>>>(part2, ROW_BLOCKS, MR2);
  k_out<<<(NPTS + 255) / 256, 256, 0, stream>>>(H2, MR2, g2, be2, out);
}

// Round 7
// 523.021 us; speedup vs baseline: 1.0325x; 1.0325x over previous
//
#include <hip/hip_runtime.h>
#include <math.h>
#include <float.h>
#include <stdint.h>

#define B_ 4
#define N_ 8192
#define K_ 9
#define NPTS (B_ * N_)           // 32768
#define NROWS (NPTS * K_)        // 294912
#define SPLIT 16
#define CHUNK (N_ / SPLIT)       // 512
#define NGROUP 16
#define GSIZE (CHUNK / NGROUP)   // 32
#define ROW_BLOCKS (NROWS / 256) // 1152

// Distance: EXACT source shape of rounds 1-4/6 (passed). Plain mul/add tree —
// identical expression tree in every kernel -> bit-identical distances
// everywhere. DO NOT rewrite with explicit fmaf / reassociation (round 5
// flipped a knife-edge 9th/10th-neighbor decision vs the reference).
__device__ __forceinline__ float dist2f(float4 q, float4 c) {
  float dot = q.x * c.x + q.y * c.y + q.z * c.z;
  return (q.w + c.w) - 2.0f * dot;
}

// ---------------- K0: pack x (B,N,3) -> float4 (x,y,z,|x|^2) -------------------
__launch_bounds__(256)
__global__ void k_pack(const float* __restrict__ x, float4* __restrict__ P) {
  int i = blockIdx.x * 256 + threadIdx.x;
  if (i >= NPTS) return;
  float a = x[3 * i], b = x[3 * i + 1], c = x[3 * i + 2];
  P[i] = make_float4(a, b, c, a * a + b * b + c * c);
}

// ---------------- K1: two-level exact top-9 per 512-chunk ----------------------
// All per-lane state in NAMED SCALARS (promote-alloca drops arrays -> scratch).
// HS (has-self) is a compile-time flag: only the 1-in-16 blocks whose chunk
// contains the query point pay the self-exclusion cndmasks.
#define GDECL(G) float gd##G; int gi##G;
#define SCANG(G)                                                           \
  { float bgd = FLT_MAX; int bgi = 0; int jg = j0 + G * GSIZE;             \
    _Pragma("clang loop unroll(disable)")                                  \
    for (int jj = 0; jj < GSIZE; jj += 4) {                                \
      int j = jg + jj;                                                     \
      float4 c0 = Pb[j], c1 = Pb[j + 1], c2 = Pb[j + 2], c3 = Pb[j + 3];   \
      float d0 = dist2f(q, c0), d1 = dist2f(q, c1);                        \
      float d2 = dist2f(q, c2), d3 = dist2f(q, c3);                        \
      if (HS) {                                                            \
        d0 = (j + 0 == n) ? FLT_MAX : d0;                                  \
        d1 = (j + 1 == n) ? FLT_MAX : d1;                                  \
        d2 = (j + 2 == n) ? FLT_MAX : d2;                                  \
        d3 = (j + 3 == n) ? FLT_MAX : d3;                                  \
      }                                                                    \
      bool l0 = d0 < bgd; bgd = l0 ? d0 : bgd; bgi = l0 ? (j + 0) : bgi;   \
      bool l1 = d1 < bgd; bgd = l1 ? d1 : bgd; bgi = l1 ? (j + 1) : bgi;   \
      bool l2 = d2 < bgd; bgd = l2 ? d2 : bgd; bgi = l2 ? (j + 2) : bgi;   \
      bool l3 = d3 < bgd; bgd = l3 ? d3 : bgd; bgi = l3 ? (j + 3) : bgi;   \
    }                                                                      \
    gd##G = bgd; gi##G = bgi; }
#define LM(G)                                                              \
  { bool lt = (gd##G < wd) | ((gd##G == wd) & (gi##G < wi));               \
    wd = lt ? gd##G : wd; wi = lt ? gi##G : wi; wg = lt ? G : wg; }
#define WBK(G)                                                             \
  { bool m = (wg == G); gd##G = m ? nd : gd##G; gi##G = m ? ni : gi##G; }

template <bool HS>
__device__ __forceinline__ void knn_chunk(const float4* __restrict__ Pb,
                                          int n, int s, int p,
                                          int* __restrict__ PBI) {
  float4 q = Pb[n];
  int j0 = s * CHUNK;

  GDECL(0) GDECL(1) GDECL(2) GDECL(3) GDECL(4) GDECL(5) GDECL(6) GDECL(7)
  GDECL(8) GDECL(9) GDECL(10) GDECL(11) GDECL(12) GDECL(13) GDECL(14) GDECL(15)

  SCANG(0) SCANG(1) SCANG(2) SCANG(3) SCANG(4) SCANG(5) SCANG(6) SCANG(7)
  SCANG(8) SCANG(9) SCANG(10) SCANG(11) SCANG(12) SCANG(13) SCANG(14) SCANG(15)

#pragma clang loop unroll(disable)
  for (int r = 0; r < K_; ++r) {
    // lexicographic min over the 16 records
    float wd = gd0; int wi = gi0; int wg = 0;
    LM(1) LM(2) LM(3) LM(4) LM(5) LM(6) LM(7)
    LM(8) LM(9) LM(10) LM(11) LM(12) LM(13) LM(14) LM(15)
    PBI[(size_t)(s * K_ + r) * NPTS + p] = wi;   // coalesced across lanes

    // refill winning group: lex-min over keys strictly > (wd, wi)
    int base = j0 + wg * GSIZE;
    float nd = FLT_MAX; int ni = 0;
#pragma clang loop unroll(disable)
    for (int jj = 0; jj < GSIZE; jj += 4) {
      int j = base + jj;
      float4 c0 = Pb[j], c1 = Pb[j + 1], c2 = Pb[j + 2], c3 = Pb[j + 3];
      float d0 = dist2f(q, c0), d1 = dist2f(q, c1);
      float d2 = dist2f(q, c2), d3 = dist2f(q, c3);
      if (HS) {
        d0 = (j + 0 == n) ? FLT_MAX : d0;
        d1 = (j + 1 == n) ? FLT_MAX : d1;
        d2 = (j + 2 == n) ? FLT_MAX : d2;
        d3 = (j + 3 == n) ? FLT_MAX : d3;
      }
      bool k0 = (d0 > wd) | ((d0 == wd) & ((j + 0) > wi));
      bool k1 = (d1 > wd) | ((d1 == wd) & ((j + 1) > wi));
      bool k2 = (d2 > wd) | ((d2 == wd) & ((j + 2) > wi));
      bool k3 = (d3 > wd) | ((d3 == wd) & ((j + 3) > wi));
      d0 = k0 ? d0 : FLT_MAX;
      d1 = k1 ? d1 : FLT_MAX;
      d2 = k2 ? d2 : FLT_MAX;
      d3 = k3 ? d3 : FLT_MAX;
      bool l0 = d0 < nd; nd = l0 ? d0 : nd; ni = l0 ? (j + 0) : ni;
      bool l1 = d1 < nd; nd = l1 ? d1 : nd; ni = l1 ? (j + 1) : ni;
      bool l2 = d2 < nd; nd = l2 ? d2 : nd; ni = l2 ? (j + 2) : ni;
      bool l3 = d3 < nd; nd = l3 ? d3 : nd; ni = l3 ? (j + 3) : ni;
    }
    WBK(0) WBK(1) WBK(2) WBK(3) WBK(4) WBK(5) WBK(6) WBK(7)
    WBK(8) WBK(9) WBK(10) WBK(11) WBK(12) WBK(13) WBK(14) WBK(15)
  }
}

__launch_bounds__(256, 8)
__global__ void k_knn2(const float4* __restrict__ P, int* __restrict__ PBI) {
  int bid = blockIdx.x;
  int pq = bid >> 4;                 // point-quad [0,128): 256 points
  int s = bid & (SPLIT - 1);
  int p = pq * 256 + threadIdx.x;
  int b = p >> 13;                   // batch (block-uniform: 256-aligned range)
  int n = p & (N_ - 1);
  const float4* __restrict__ Pb = P + b * N_;
  int n0 = (pq * 256) & (N_ - 1);    // block-uniform; chunk = n0>>9 (512-chunk)
  if (s == (n0 >> 9)) knn_chunk<true>(Pb, n, s, p, PBI);
  else                knn_chunk<false>(Pb, n, s, p, PBI);
}

// Register-resident sorted top-9 insert (named scalars).
#define LVL(bdv, biv)                                                     \
  { bool lt = cd < (bdv); float td = (bdv); int ti = (biv);               \
    (bdv) = lt ? cd : (bdv); (biv) = lt ? ci : (biv);                     \
    cd = lt ? td : cd; ci = lt ? ti : ci; }
#define INS9ALL()                                                         \
  LVL(b0d, b0i) LVL(b1d, b1i) LVL(b2d, b2i) LVL(b3d, b3i) LVL(b4d, b4i)  \
  LVL(b5d, b5i) LVL(b6d, b6i) LVL(b7d, b7i) LVL(b8d, b8i)
#define TOP9_DECL()                                                       \
  float b0d = FLT_MAX, b1d = FLT_MAX, b2d = FLT_MAX, b3d = FLT_MAX,       \
        b4d = FLT_MAX, b5d = FLT_MAX, b6d = FLT_MAX, b7d = FLT_MAX,       \
        b8d = FLT_MAX;                                                    \
  int b0i = 0, b1i = 0, b2i = 0, b3i = 0, b4i = 0, b5i = 0, b6i = 0,      \
      b7i = 0, b8i = 0;

// ---------------- K2a: merge 4 sorted lists of 9 -> sorted 9 -------------------
// Wave w of each 256-thread block merges chunk-group g=w (chunks 4w..4w+3)
// for 64 points. Ascending (chunk, rank) + strict-< insertion = exact lex
// (d, index) order (chunks are ascending index ranges).
__launch_bounds__(256)
__global__ void k_merge1(const float4* __restrict__ P, const int* __restrict__ PBI,
                         int* __restrict__ PBI2) {
  int lane = threadIdx.x & 63, w = threadIdx.x >> 6;
  int p = blockIdx.x * 64 + lane;
  int b = p >> 13;
  int n = p & (N_ - 1);
  const float4* __restrict__ Pb = P + b * N_;
  float4 q = Pb[n];

  TOP9_DECL();
#pragma unroll 6
  for (int e = 0; e < 4 * K_; ++e) {
    int ci = PBI[(size_t)(w * 4 * K_ + e) * NPTS + p];   // coalesced
    float4 c = Pb[ci];
    float cd = dist2f(q, c);
    INS9ALL();
  }
  size_t base = (size_t)(w * K_) * NPTS + p;
  PBI2[base + 0 * (size_t)NPTS] = b0i;
  PBI2[base + 1 * (size_t)NPTS] = b1i;
  PBI2[base + 2 * (size_t)NPTS] = b2i;
  PBI2[base + 3 * (size_t)NPTS] = b3i;
  PBI2[base + 4 * (size_t)NPTS] = b4i;
  PBI2[base + 5 * (size_t)NPTS] = b5i;
  PBI2[base + 6 * (size_t)NPTS] = b6i;
  PBI2[base + 7 * (size_t)NPTS] = b7i;
  PBI2[base + 8 * (size_t)NPTS] = b8i;
}

#define MKREL(T)                                                          \
  float rx##T, ry##T, rz##T, ph##T;                                       \
  { float4 m = Pb[b##T##i];                                               \
    rx##T = m.x - q.x; ry##T = m.y - q.y; rz##T = m.z - q.z;              \
    ph##T = atan2f(ry##T, rx##T); }

#define CE(A, Bv)                                                         \
  { bool lt = ph##Bv < ph##A; float t0;                                   \
    t0 = ph##A; ph##A = lt ? ph##Bv : t0; ph##Bv = lt ? t0 : ph##Bv;      \
    t0 = rx##A; rx##A = lt ? rx##Bv : t0; rx##Bv = lt ? t0 : rx##Bv;      \
    t0 = ry##A; ry##A = lt ? ry##Bv : t0; ry##Bv = lt ? t0 : ry##Bv;      \
    t0 = rz##A; rz##A = lt ? rz##Bv : t0; rz##Bv = lt ? t0 : rz##Bv; }

#define STREL(T)                                                          \
  { REL[(size_t)(0 * K_ + T) * NPTS + p] = rx##T;                         \
    REL[(size_t)(1 * K_ + T) * NPTS + p] = ry##T;                         \
    REL[(size_t)(2 * K_ + T) * NPTS + p] = rz##T; }

// ---------------- K2b: final merge (4x9), phi-sort, sign -----------------------
__launch_bounds__(64)
__global__ void k_merge2(const float4* __restrict__ P, const int* __restrict__ PBI2,
                         float* __restrict__ REL, float* __restrict__ SGN) {
  int p = blockIdx.x * 64 + threadIdx.x;
  int b = p >> 13;
  int n = p & (N_ - 1);
  const float4* __restrict__ Pb = P + b * N_;
  float4 q = Pb[n];

  TOP9_DECL();
#pragma unroll 6
  for (int e = 0; e < 4 * K_; ++e) {
    int ci = PBI2[(size_t)e * NPTS + p];        // coalesced
    float4 c = Pb[ci];
    float cd = dist2f(q, c);
    INS9ALL();
  }

  MKREL(0) MKREL(1) MKREL(2) MKREL(3) MKREL(4)
  MKREL(5) MKREL(6) MKREL(7) MKREL(8)

  // stable insertion-sort network ascending by phi (36 strict-< CEs)
  CE(0,1)
  CE(1,2) CE(0,1)
  CE(2,3) CE(1,2) CE(0,1)
  CE(3,4) CE(2,3) CE(1,2) CE(0,1)
  CE(4,5) CE(3,4) CE(2,3) CE(1,2) CE(0,1)
  CE(5,6) CE(4,5) CE(3,4) CE(2,3) CE(1,2) CE(0,1)
  CE(6,7) CE(5,6) CE(4,5) CE(3,4) CE(2,3) CE(1,2) CE(0,1)
  CE(7,8) CE(6,7) CE(5,6) CE(4,5) CE(3,4) CE(2,3) CE(1,2) CE(0,1)

  // sign from triangle 0's NORMALIZED nx (reference semantics)
  float nx0 = ry0 * rz1 - rz0 * ry1;
  float ny0 = rz0 * rx1 - rx0 * rz1;
  float nz0 = rx0 * ry1 - ry0 * rx1;
  float nrm0 = sqrtf(nx0 * nx0 + ny0 * ny0 + nz0 * nz0) + 1e-6f;
  SGN[p] = ((nx0 / nrm0) > 0.0f) ? 1.0f : -1.0f;

  STREL(0) STREL(1) STREL(2) STREL(3) STREL(4)
  STREL(5) STREL(6) STREL(7) STREL(8)
}

// ---------------- K3: per-row features + @W1+b1 -> H1 (chan-major) + stats -----
__launch_bounds__(256)
__global__ void k_featrow(const float* __restrict__ REL, const float* __restrict__ SGN,
                          const float* __restrict__ W1, const float* __restrict__ b1,
                          float* __restrict__ H1, double* __restrict__ part1) {
  int r = blockIdx.x * 256 + threadIdx.x;   // row id = t*NPTS + p
  int t = r >> 15;                          // / NPTS
  int p = r & (NPTS - 1);
  int t2 = (t + 1 == K_) ? 0 : t + 1;

  float v1x = REL[(size_t)(0 * K_ + t) * NPTS + p];
  float v1y = REL[(size_t)(1 * K_ + t) * NPTS + p];
  float v1z = REL[(size_t)(2 * K_ + t) * NPTS + p];
  float v2x = REL[(size_t)(0 * K_ + t2) * NPTS + p];
  float v2y = REL[(size_t)(1 * K_ + t2) * NPTS + p];
  float v2z = REL[(size_t)(2 * K_ + t2) * NPTS + p];
  float sgn = SGN[p];

  float cx = 0.5f * (v1x + v2x);
  float cy = 0.5f * (v1y + v2y);
  float cz = 0.5f * (v1z + v2z);
  float nx = v1y * v2z - v1z * v2y;
  float ny = v1z * v2x - v1x * v2z;
  float nz = v1x * v2y - v1y * v2x;
  float nrm = sqrtf(nx * nx + ny * ny + nz * nz) + 1e-6f;
  nx /= nrm; ny /= nrm; nz /= nrm;
  nx *= sgn; ny *= sgn; nz *= sgn;
  float pos = (nx * cx + ny * cy + nz * cz) / 1.7320508075688772f;

  float fv[7] = {cx, cy, cz, nx, ny, nz, pos};
  float o[10];
#pragma unroll
  for (int c = 0; c < 10; ++c) {
    float h = b1[c];
#pragma unroll
    for (int rr = 0; rr < 7; ++rr) h = fmaf(fv[rr], W1[rr * 10 + c], h);
    o[c] = h;
    H1[(size_t)c * NROWS + r] = h;          // coalesced
  }

  __shared__ double sred[4][20];
  int lane = threadIdx.x & 63, wv = threadIdx.x >> 6;
#pragma unroll
  for (int c = 0; c < 10; ++c) {
    double a = (double)o[c];
#pragma unroll
    for (int off = 32; off > 0; off >>= 1) a += __shfl_down(a, off);
    if (lane == 0) sred[wv][c] = a;
    double qq = (double)o[c] * (double)o[c];
#pragma unroll
    for (int off = 32; off > 0; off >>= 1) qq += __shfl_down(qq, off);
    if (lane == 0) sred[wv][10 + c] = qq;
  }
  __syncthreads();
  if (threadIdx.x < 20) {
    part1[(size_t)blockIdx.x * 20 + threadIdx.x] =
        sred[0][threadIdx.x] + sred[1][threadIdx.x] +
        sred[2][threadIdx.x] + sred[3][threadIdx.x];
  }
}

// ---------------- K4: reduce partials (10 blocks, one channel pair each) --------
__launch_bounds__(256)
__global__ void k_reduce(const double* __restrict__ part, int nblk,
                         float* __restrict__ MR) {
  int c = blockIdx.x;          // 0..9
  int tid = threadIdx.x;
  double sA = 0.0, sB = 0.0;
  for (int i = tid; i < nblk; i += 256) {
    sA += part[(size_t)i * 20 + c];
    sB += part[(size_t)i * 20 + 10 + c];
  }
  __shared__ double redA[256], redB[256];
  redA[tid] = sA; redB[tid] = sB;
  __syncthreads();
  for (int off = 128; off > 0; off >>= 1) {
    if (tid < off) { redA[tid] += redA[tid + off]; redB[tid] += redB[tid + off]; }
    __syncthreads();
  }
  if (tid == 0) {
    double mu = redA[0] / (double)NROWS;
    double var = redB[0] / (double)NROWS - mu * mu;
    MR[c] = (float)mu;
    MR[10 + c] = (float)(1.0 / sqrt(var + 1e-5));
  }
}

// ---------------- K5: bn1 + relu + @W2+b2 -> H2 (chan-major) + stats ------------
__launch_bounds__(256)
__global__ void k_mlp2(const float* __restrict__ H1, const float* __restrict__ MR1,
                       const float* __restrict__ g1, const float* __restrict__ be1,
                       const float* __restrict__ W2, const float* __restrict__ b2,
                       float* __restrict__ H2, double* __restrict__ part2) {
  int r = blockIdx.x * 256 + threadIdx.x;
  float v[10];
#pragma unroll
  for (int c = 0; c < 10; ++c) {
    float h = H1[(size_t)c * NROWS + r];
    float z = g1[c] * (h - MR1[c]) * MR1[10 + c] + be1[c];
    v[c] = z > 0.0f ? z : 0.0f;
  }
  float o[10];
#pragma unroll
  for (int c = 0; c < 10; ++c) {
    float h = b2[c];
#pragma unroll
    for (int t = 0; t < 10; ++t) h = fmaf(v[t], W2[t * 10 + c], h);
    o[c] = h;
    H2[(size_t)c * NROWS + r] = h;
  }

  __shared__ double sred[4][20];
  int lane = threadIdx.x & 63, wv = threadIdx.x >> 6;
#pragma unroll
  for (int c = 0; c < 10; ++c) {
    double a = (double)o[c];
#pragma unroll
    for (int off = 32; off > 0; off >>= 1) a += __shfl_down(a, off);
    if (lane == 0) sred[wv][c] = a;
    double qq = (double)o[c] * (double)o[c];
#pragma unroll
    for (int off = 32; off > 0; off >>= 1) qq += __shfl_down(qq, off);
    if (lane == 0) sred[wv][10 + c] = qq;
  }
  __syncthreads();
  if (threadIdx.x < 20) {
    part2[(size_t)blockIdx.x * 20 + threadIdx.x] =
        sred[0][threadIdx.x] + sred[1][threadIdx.x] +
        sred[2][threadIdx.x] + sred[3][threadIdx.x];
  }
}

// ---------------- K6: bn2 + relu + max over k -> out ----------------------------
__launch_bounds__(256)
__global__ void k_out(const float* __restrict__ H2, const float* __restrict__ MR2,
                      const float* __restrict__ g2, const float* __restrict__ be2,
                      float* __restrict__ out) {
  int p = blockIdx.x * 256 + threadIdx.x;
  if (p >= NPTS) return;
#pragma unroll
  for (int c = 0; c < 10; ++c) {
    float m = -FLT_MAX;
#pragma unroll
    for (int j = 0; j < K_; ++j) {
      float h = H2[(size_t)c * NROWS + j * NPTS + p];   // coalesced
      float z = g2[c] * (h - MR2[c]) * MR2[10 + c] + be2[c];
      z = z > 0.0f ? z : 0.0f;
      m = fmaxf(m, z);
    }
    out[(size_t)p * 10 + c] = m;
  }
}

extern "C" void kernel_launch(void* const* d_in, const int* in_sizes, int n_in,
                              void* d_out, int out_size, void* d_ws, size_t ws_size,
                              hipStream_t stream) {
  (void)in_sizes; (void)n_in; (void)out_size; (void)ws_size;
  const float* x  = (const float*)d_in[0];
  const float* W1 = (const float*)d_in[1];
  const float* b1 = (const float*)d_in[2];
  const float* g1 = (const float*)d_in[3];
  const float* be1= (const float*)d_in[4];
  const float* W2 = (const float*)d_in[5];
  const float* b2 = (const float*)d_in[6];
  const float* g2 = (const float*)d_in[7];
  const float* be2= (const float*)d_in[8];
  float* out = (float*)d_out;

  char* base = (char*)d_ws;
  float4* P   = (float4*)base;                                   // 512 KB
  int*    PBI = (int*)(base + (size_t)NPTS * 16);                // 144 slices, 18.9 MB
  float*  REL = (float*)((char*)PBI + (size_t)SPLIT * K_ * NPTS * 4);  // 27 slices
  float*  SGN = REL + (size_t)3 * K_ * NPTS;                     // 128 KB
  float*  H1  = SGN + NPTS;                                      // 11.8 MB
  double* part1 = (double*)(H1 + (size_t)10 * NROWS);            // 1152*20 dbl
  float*  MR1 = (float*)(part1 + (size_t)ROW_BLOCKS * 20);
  float*  MR2 = MR1 + 32;
  // PBI2 aliases H1's head (dead before k_featrow writes H1);
  // H2 + part2 alias PBI (dead after k_merge1)
  int*    PBI2 = (int*)H1;                                       // 36 slices, 4.7 MB
  float*  H2 = (float*)PBI;                                      // 11.8 of 18.9 MB
  double* part2 = (double*)((char*)PBI + 12 * 1024 * 1024);

  k_pack<<<NPTS / 256, 256, 0, stream>>>(x, P);
  k_knn2<<<(NPTS / 256) * SPLIT, 256, 0, stream>>>(P, PBI);
  k_merge1<<<NPTS / 64, 256, 0, stream>>>(P, PBI, PBI2);
  k_merge2<<<NPTS / 64, 64, 0, stream>>>(P, PBI2, REL, SGN);
  k_featrow<<<ROW_BLOCKS, 256, 0, stream>>>(REL, SGN, W1, b1, H1, part1);
  k_reduce<<<10, 256, 0, stream>>>(part1, ROW_BLOCKS, MR1);
  k_mlp2<<<ROW_BLOCKS, 256, 0, stream>>>(H1, MR1, g1, be1, W2, b2, H2, part2);
  k_reduce<<<10, 256, 0, stream>>>(part2, ROW_BLOCKS, MR2);
  k_out<<<NPTS / 256, 256, 0, stream>>>(H2, MR2, g2, be2, out);
}

// Round 8
// 304.217 us; speedup vs baseline: 1.7751x; 1.7192x over previous
//
#include <hip/hip_runtime.h>
#include <math.h>
#include <float.h>
#include <stdint.h>

#define B_ 4
#define N_ 8192
#define K_ 9
#define NPTS (B_ * N_)           // 32768
#define NROWS (NPTS * K_)        // 294912
#define SPLIT 8
#define CHUNK (N_ / SPLIT)       // 1024
#define NGROUP 16
#define GSIZE (CHUNK / NGROUP)   // 64
#define GSTRIDE 65               // +1 float4 pad -> refill groups hit distinct banks
#define ROW_BLOCKS (NROWS / 256) // 1152

// Distance: EXACT source shape of rounds 1-4/6/7 (passed). Plain mul/add tree —
// identical expression tree in every kernel -> bit-identical distances
// everywhere. DO NOT rewrite with explicit fmaf / reassociation (round 5
// flipped a knife-edge 9th/10th-neighbor decision vs the reference).
__device__ __forceinline__ float dist2f(float4 q, float4 c) {
  float dot = q.x * c.x + q.y * c.y + q.z * c.z;
  return (q.w + c.w) - 2.0f * dot;
}

// ---------------- K0: pack x (B,N,3) -> float4 (x,y,z,|x|^2) -------------------
__launch_bounds__(256)
__global__ void k_pack(const float* __restrict__ x, float4* __restrict__ P) {
  int i = blockIdx.x * 256 + threadIdx.x;
  if (i >= NPTS) return;
  float a = x[3 * i], b = x[3 * i + 1], c = x[3 * i + 2];
  P[i] = make_float4(a, b, c, a * a + b * b + c * c);
}

// ---------------- K1: two-level exact top-9 per 1024-chunk, LDS-staged ----------
// Named scalars for all per-lane state (promote-alloca drops arrays to scratch;
// launch_bounds(256,4) keeps a 128-reg budget so records fit — round 7's (256,8)
// capped at 64 and spilled 31 MB to scratch).
#define GDECL(G) float gd##G; int gi##G;
#define SCANG(G)                                                           \
  { float bgd = FLT_MAX; int bgi = 0;                                      \
    _Pragma("clang loop unroll(disable)")                                  \
    for (int jj = 0; jj < GSIZE; jj += 4) {                                \
      const float4* cp = CH + (G * GSTRIDE + jj);                          \
      float4 c0 = cp[0], c1 = cp[1], c2 = cp[2], c3 = cp[3];               \
      int j = G * GSIZE + jj;                                              \
      float d0 = dist2f(q, c0), d1 = dist2f(q, c1);                        \
      float d2 = dist2f(q, c2), d3 = dist2f(q, c3);                        \
      if (HS) {                                                            \
        d0 = (j + 0 == nl) ? FLT_MAX : d0;                                 \
        d1 = (j + 1 == nl) ? FLT_MAX : d1;                                 \
        d2 = (j + 2 == nl) ? FLT_MAX : d2;                                 \
        d3 = (j + 3 == nl) ? FLT_MAX : d3;                                 \
      }                                                                    \
      bool l0 = d0 < bgd; bgd = l0 ? d0 : bgd; bgi = l0 ? (j + 0) : bgi;   \
      bool l1 = d1 < bgd; bgd = l1 ? d1 : bgd; bgi = l1 ? (j + 1) : bgi;   \
      bool l2 = d2 < bgd; bgd = l2 ? d2 : bgd; bgi = l2 ? (j + 2) : bgi;   \
      bool l3 = d3 < bgd; bgd = l3 ? d3 : bgd; bgi = l3 ? (j + 3) : bgi;   \
    }                                                                      \
    gd##G = bgd; gi##G = bgi; }
#define LM(G)                                                              \
  { bool lt = (gd##G < wd) | ((gd##G == wd) & (gi##G < wi));               \
    wd = lt ? gd##G : wd; wi = lt ? gi##G : wi; wg = lt ? G : wg; }
#define WBK(G)                                                             \
  { bool m = (wg == G); gd##G = m ? nd : gd##G; gi##G = m ? ni : gi##G; }

template <bool HS>
__device__ __forceinline__ void knn_chunk(const float4* CH, float4 q, int nl,
                                          int j0, int s, int p,
                                          float* __restrict__ PBD,
                                          int* __restrict__ PBI) {
  GDECL(0) GDECL(1) GDECL(2) GDECL(3) GDECL(4) GDECL(5) GDECL(6) GDECL(7)
  GDECL(8) GDECL(9) GDECL(10) GDECL(11) GDECL(12) GDECL(13) GDECL(14) GDECL(15)

  SCANG(0) SCANG(1) SCANG(2) SCANG(3) SCANG(4) SCANG(5) SCANG(6) SCANG(7)
  SCANG(8) SCANG(9) SCANG(10) SCANG(11) SCANG(12) SCANG(13) SCANG(14) SCANG(15)

#pragma clang loop unroll(disable)
  for (int r = 0; r < K_; ++r) {
    // lexicographic min over the 16 records (local indices; local order ==
    // global order within the chunk)
    float wd = gd0; int wi = gi0; int wg = 0;
    LM(1) LM(2) LM(3) LM(4) LM(5) LM(6) LM(7)
    LM(8) LM(9) LM(10) LM(11) LM(12) LM(13) LM(14) LM(15)
    PBD[(size_t)(s * K_ + r) * NPTS + p] = wd;        // coalesced
    PBI[(size_t)(s * K_ + r) * NPTS + p] = j0 + wi;   // coalesced, global idx

    // refill winning group: lex-min over keys strictly > (wd, wi)
    int ab = wg * GSTRIDE;   // per-lane LDS base (float4 units)
    int jb = wg * GSIZE;     // per-lane local index base
    float nd = FLT_MAX; int ni = 0;
#pragma clang loop unroll(disable)
    for (int jj = 0; jj < GSIZE; jj += 4) {
      const float4* cp = CH + (ab + jj);
      float4 c0 = cp[0], c1 = cp[1], c2 = cp[2], c3 = cp[3];
      int j = jb + jj;
      float d0 = dist2f(q, c0), d1 = dist2f(q, c1);
      float d2 = dist2f(q, c2), d3 = dist2f(q, c3);
      if (HS) {
        d0 = (j + 0 == nl) ? FLT_MAX : d0;
        d1 = (j + 1 == nl) ? FLT_MAX : d1;
        d2 = (j + 2 == nl) ? FLT_MAX : d2;
        d3 = (j + 3 == nl) ? FLT_MAX : d3;
      }
      bool k0 = (d0 > wd) | ((d0 == wd) & ((j + 0) > wi));
      bool k1 = (d1 > wd) | ((d1 == wd) & ((j + 1) > wi));
      bool k2 = (d2 > wd) | ((d2 == wd) & ((j + 2) > wi));
      bool k3 = (d3 > wd) | ((d3 == wd) & ((j + 3) > wi));
      d0 = k0 ? d0 : FLT_MAX;
      d1 = k1 ? d1 : FLT_MAX;
      d2 = k2 ? d2 : FLT_MAX;
      d3 = k3 ? d3 : FLT_MAX;
      bool l0 = d0 < nd; nd = l0 ? d0 : nd; ni = l0 ? (j + 0) : ni;
      bool l1 = d1 < nd; nd = l1 ? d1 : nd; ni = l1 ? (j + 1) : ni;
      bool l2 = d2 < nd; nd = l2 ? d2 : nd; ni = l2 ? (j + 2) : ni;
      bool l3 = d3 < nd; nd = l3 ? d3 : nd; ni = l3 ? (j + 3) : ni;
    }
    WBK(0) WBK(1) WBK(2) WBK(3) WBK(4) WBK(5) WBK(6) WBK(7)
    WBK(8) WBK(9) WBK(10) WBK(11) WBK(12) WBK(13) WBK(14) WBK(15)
  }
}

__launch_bounds__(256, 4)
__global__ void k_knn2(const float4* __restrict__ P, float* __restrict__ PBD,
                       int* __restrict__ PBI) {
  __shared__ float4 CH[NGROUP * GSTRIDE];   // 16640 B
  int bid = blockIdx.x;
  int pq = bid >> 3;                 // 256-point range [0,128)
  int s = bid & (SPLIT - 1);
  int p = pq * 256 + threadIdx.x;
  int b = p >> 13;                   // block-uniform (256-aligned range)
  int n = p & (N_ - 1);
  const float4* __restrict__ Pb = P + b * N_;
  int j0 = s * CHUNK;

  // stage chunk -> LDS (coalesced; padded group stride)
  for (int t = threadIdx.x; t < CHUNK; t += 256) {
    CH[(t >> 6) * GSTRIDE + (t & 63)] = Pb[j0 + t];
  }
  float4 q = Pb[n];
  __syncthreads();

  int n0 = (pq * 256) & (N_ - 1);    // block-uniform; chunk containing queries
  int nl = n - j0;                   // local self index (valid only if HS)
  if (s == (n0 >> 10)) knn_chunk<true >(CH, q, nl, j0, s, p, PBD, PBI);
  else                 knn_chunk<false>(CH, q, nl, j0, s, p, PBD, PBI);
}

// Register-resident sorted top-9 insert (named scalars).
#define LVL(bdv, biv)                                                     \
  { bool lt = cd < (bdv); float td = (bdv); int ti = (biv);               \
    (bdv) = lt ? cd : (bdv); (biv) = lt ? ci : (biv);                     \
    cd = lt ? td : cd; ci = lt ? ti : ci; }
#define INS9ALL()                                                         \
  LVL(b0d, b0i) LVL(b1d, b1i) LVL(b2d, b2i) LVL(b3d, b3i) LVL(b4d, b4i)  \
  LVL(b5d, b5i) LVL(b6d, b6i) LVL(b7d, b7i) LVL(b8d, b8i)
#define TOP9_DECL()                                                       \
  float b0d = FLT_MAX, b1d = FLT_MAX, b2d = FLT_MAX, b3d = FLT_MAX,       \
        b4d = FLT_MAX, b5d = FLT_MAX, b6d = FLT_MAX, b7d = FLT_MAX,       \
        b8d = FLT_MAX;                                                    \
  int b0i = 0, b1i = 0, b2i = 0, b3i = 0, b4i = 0, b5i = 0, b6i = 0,      \
      b7i = 0, b8i = 0;

#define MKREL(T)                                                          \
  float rx##T, ry##T, rz##T, ph##T;                                       \
  { float4 m = Pb[b##T##i];                                               \
    rx##T = m.x - q.x; ry##T = m.y - q.y; rz##T = m.z - q.z;              \
    ph##T = atan2f(ry##T, rx##T); }

#define CE(A, Bv)                                                         \
  { bool lt = ph##Bv < ph##A; float t0;                                   \
    t0 = ph##A; ph##A = lt ? ph##Bv : t0; ph##Bv = lt ? t0 : ph##Bv;      \
    t0 = rx##A; rx##A = lt ? rx##Bv : t0; rx##Bv = lt ? t0 : rx##Bv;      \
    t0 = ry##A; ry##A = lt ? ry##Bv : t0; ry##Bv = lt ? t0 : ry##Bv;      \
    t0 = rz##A; rz##A = lt ? rz##Bv : t0; rz##Bv = lt ? t0 : rz##Bv; }

#define FEAT(T, U)                                                        \
  { float cx = 0.5f * (rx##T + rx##U);                                    \
    float cy = 0.5f * (ry##T + ry##U);                                    \
    float cz = 0.5f * (rz##T + rz##U);                                    \
    float nx = ry##T * rz##U - rz##T * ry##U;                             \
    float ny = rz##T * rx##U - rx##T * rz##U;                             \
    float nz = rx##T * ry##U - ry##T * rx##U;                             \
    float nrm = sqrtf(nx * nx + ny * ny + nz * nz) + 1e-6f;               \
    nx /= nrm; ny /= nrm; nz /= nrm;                                      \
    nx *= sgn; ny *= sgn; nz *= sgn;                                      \
    float pos = (nx * cx + ny * cy + nz * cz) / 1.7320508075688772f;      \
    float fv[7] = {cx, cy, cz, nx, ny, nz, pos};                          \
    _Pragma("unroll")                                                     \
    for (int c = 0; c < 10; ++c) {                                        \
      float h = b1[c];                                                    \
      _Pragma("unroll")                                                   \
      for (int rr = 0; rr < 7; ++rr) h = fmaf(fv[rr], W1[rr * 10 + c], h);\
      H1[(size_t)c * NROWS + (size_t)T * NPTS + p] = h;                   \
      double hd = (double)h;                                              \
      sum[c] += hd; ss[c] += hd * hd;                                     \
    } }

// ---------------- K2: merge 8 sorted lists (coalesced d+i), phi-sort, features,
//                      W1 matmul, H1 (chan-major) + stats — all fused ----------
__launch_bounds__(256)
__global__ void k_merge(const float4* __restrict__ P, const float* __restrict__ PBD,
                        const int* __restrict__ PBI,
                        const float* __restrict__ W1, const float* __restrict__ b1,
                        float* __restrict__ H1, double* __restrict__ part1) {
  int p = blockIdx.x * 256 + threadIdx.x;
  int b = p >> 13;
  int n = p & (N_ - 1);
  const float4* __restrict__ Pb = P + b * N_;
  float4 q = Pb[n];

  // ascending (chunk, rank) order + strict-< insertion = exact lex (d, index)
  // top-9 with top_k tie-breaking (chunks are ascending index ranges).
  TOP9_DECL();
#pragma unroll 8
  for (int t = 0; t < SPLIT * K_; ++t) {
    float cd = PBD[(size_t)t * NPTS + p];       // coalesced
    int ci = PBI[(size_t)t * NPTS + p];         // coalesced
    INS9ALL();
  }

  MKREL(0) MKREL(1) MKREL(2) MKREL(3) MKREL(4)
  MKREL(5) MKREL(6) MKREL(7) MKREL(8)

  // stable insertion-sort network ascending by phi (36 strict-< CEs)
  CE(0,1)
  CE(1,2) CE(0,1)
  CE(2,3) CE(1,2) CE(0,1)
  CE(3,4) CE(2,3) CE(1,2) CE(0,1)
  CE(4,5) CE(3,4) CE(2,3) CE(1,2) CE(0,1)
  CE(5,6) CE(4,5) CE(3,4) CE(2,3) CE(1,2) CE(0,1)
  CE(6,7) CE(5,6) CE(4,5) CE(3,4) CE(2,3) CE(1,2) CE(0,1)
  CE(7,8) CE(6,7) CE(5,6) CE(4,5) CE(3,4) CE(2,3) CE(1,2) CE(0,1)

  // sign from triangle 0's NORMALIZED nx (reference semantics)
  float sgn;
  { float nx0 = ry0 * rz1 - rz0 * ry1;
    float ny0 = rz0 * rx1 - rx0 * rz1;
    float nz0 = rx0 * ry1 - ry0 * rx1;
    float nrm0 = sqrtf(nx0 * nx0 + ny0 * ny0 + nz0 * nz0) + 1e-6f;
    sgn = ((nx0 / nrm0) > 0.0f) ? 1.0f : -1.0f; }

  double sum[10], ss[10];
#pragma unroll
  for (int c = 0; c < 10; ++c) { sum[c] = 0.0; ss[c] = 0.0; }

  FEAT(0,1) FEAT(1,2) FEAT(2,3) FEAT(3,4) FEAT(4,5)
  FEAT(5,6) FEAT(6,7) FEAT(7,8) FEAT(8,0)

  __shared__ double sred[4][20];
  int lane = threadIdx.x & 63, wv = threadIdx.x >> 6;
#pragma unroll
  for (int c = 0; c < 10; ++c) {
    double a = sum[c];
#pragma unroll
    for (int off = 32; off > 0; off >>= 1) a += __shfl_down(a, off);
    if (lane == 0) sred[wv][c] = a;
    double qq = ss[c];
#pragma unroll
    for (int off = 32; off > 0; off >>= 1) qq += __shfl_down(qq, off);
    if (lane == 0) sred[wv][10 + c] = qq;
  }
  __syncthreads();
  if (threadIdx.x < 20) {
    part1[(size_t)blockIdx.x * 20 + threadIdx.x] =
        sred[0][threadIdx.x] + sred[1][threadIdx.x] +
        sred[2][threadIdx.x] + sred[3][threadIdx.x];
  }
}

// ---------------- K3: reduce partials (10 blocks, one channel each) ------------
__launch_bounds__(256)
__global__ void k_reduce(const double* __restrict__ part, int nblk,
                         float* __restrict__ MR) {
  int c = blockIdx.x;          // 0..9
  int tid = threadIdx.x;
  double sA = 0.0, sB = 0.0;
  for (int i = tid; i < nblk; i += 256) {
    sA += part[(size_t)i * 20 + c];
    sB += part[(size_t)i * 20 + 10 + c];
  }
  __shared__ double redA[256], redB[256];
  redA[tid] = sA; redB[tid] = sB;
  __syncthreads();
  for (int off = 128; off > 0; off >>= 1) {
    if (tid < off) { redA[tid] += redA[tid + off]; redB[tid] += redB[tid + off]; }
    __syncthreads();
  }
  if (tid == 0) {
    double mu = redA[0] / (double)NROWS;
    double var = redB[0] / (double)NROWS - mu * mu;
    MR[c] = (float)mu;
    MR[10 + c] = (float)(1.0 / sqrt(var + 1e-5));
  }
}

// ---------------- K4: bn1 + relu + @W2+b2 -> H2 (chan-major) + stats ------------
__launch_bounds__(256)
__global__ void k_mlp2(const float* __restrict__ H1, const float* __restrict__ MR1,
                       const float* __restrict__ g1, const float* __restrict__ be1,
                       const float* __restrict__ W2, const float* __restrict__ b2,
                       float* __restrict__ H2, double* __restrict__ part2) {
  int r = blockIdx.x * 256 + threadIdx.x;
  float v[10];
#pragma unroll
  for (int c = 0; c < 10; ++c) {
    float h = H1[(size_t)c * NROWS + r];
    float z = g1[c] * (h - MR1[c]) * MR1[10 + c] + be1[c];
    v[c] = z > 0.0f ? z : 0.0f;
  }
  float o[10];
#pragma unroll
  for (int c = 0; c < 10; ++c) {
    float h = b2[c];
#pragma unroll
    for (int t = 0; t < 10; ++t) h = fmaf(v[t], W2[t * 10 + c], h);
    o[c] = h;
    H2[(size_t)c * NROWS + r] = h;
  }

  __shared__ double sred[4][20];
  int lane = threadIdx.x & 63, wv = threadIdx.x >> 6;
#pragma unroll
  for (int c = 0; c < 10; ++c) {
    double a = (double)o[c];
#pragma unroll
    for (int off = 32; off > 0; off >>= 1) a += __shfl_down(a, off);
    if (lane == 0) sred[wv][c] = a;
    double qq = (double)o[c] * (double)o[c];
#pragma unroll
    for (int off = 32; off > 0; off >>= 1) qq += __shfl_down(qq, off);
    if (lane == 0) sred[wv][10 + c] = qq;
  }
  __syncthreads();
  if (threadIdx.x < 20) {
    part2[(size_t)blockIdx.x * 20 + threadIdx.x] =
        sred[0][threadIdx.x] + sred[1][threadIdx.x] +
        sred[2][threadIdx.x] + sred[3][threadIdx.x];
  }
}

// ---------------- K5: bn2 + relu + max over k -> out ----------------------------
__launch_bounds__(256)
__global__ void k_out(const float* __restrict__ H2, const float* __restrict__ MR2,
                      const float* __restrict__ g2, const float* __restrict__ be2,
                      float* __restrict__ out) {
  int p = blockIdx.x * 256 + threadIdx.x;
  if (p >= NPTS) return;
#pragma unroll
  for (int c = 0; c < 10; ++c) {
    float m = -FLT_MAX;
#pragma unroll
    for (int j = 0; j < K_; ++j) {
      float h = H2[(size_t)c * NROWS + j * NPTS + p];   // coalesced
      float z = g2[c] * (h - MR2[c]) * MR2[10 + c] + be2[c];
      z = z > 0.0f ? z : 0.0f;
      m = fmaxf(m, z);
    }
    out[(size_t)p * 10 + c] = m;
  }
}

extern "C" void kernel_launch(void* const* d_in, const int* in_sizes, int n_in,
                              void* d_out, int out_size, void* d_ws, size_t ws_size,
                              hipStream_t stream) {
  (void)in_sizes; (void)n_in; (void)out_size; (void)ws_size;
  const float* x  = (const float*)d_in[0];
  const float* W1 = (const float*)d_in[1];
  const float* b1 = (const float*)d_in[2];
  const float* g1 = (const float*)d_in[3];
  const float* be1= (const float*)d_in[4];
  const float* W2 = (const float*)d_in[5];
  const float* b2 = (const float*)d_in[6];
  const float* g2 = (const float*)d_in[7];
  const float* be2= (const float*)d_in[8];
  float* out = (float*)d_out;

  char* base = (char*)d_ws;
  float4* P   = (float4*)base;                                   // 512 KB
  float*  PBD = (float*)(base + (size_t)NPTS * 16);              // 72 slices, 9.44 MB
  int*    PBI = (int*)((char*)PBD + (size_t)SPLIT * K_ * NPTS * 4);  // 9.44 MB
  float*  H1  = (float*)((char*)PBI + (size_t)SPLIT * K_ * NPTS * 4); // 11.8 MB
  double* part1 = (double*)(H1 + (size_t)10 * NROWS);            // 128*20 dbl
  float*  MR1 = (float*)(part1 + 128 * 20);
  float*  MR2 = MR1 + 32;
  // H2 + part2 alias the PBD+PBI region (dead after k_merge)
  float*  H2 = (float*)PBD;                                      // 11.8 of 18.9 MB
  double* part2 = (double*)((char*)PBD + 12 * 1024 * 1024);

  k_pack<<<NPTS / 256, 256, 0, stream>>>(x, P);
  k_knn2<<<(NPTS / 256) * SPLIT, 256, 0, stream>>>(P, PBD, PBI);
  k_merge<<<NPTS / 256, 256, 0, stream>>>(P, PBD, PBI, W1, b1, H1, part1);
  k_reduce<<<10, 256, 0, stream>>>(part1, NPTS / 256, MR1);
  k_mlp2<<<ROW_BLOCKS, 256, 0, stream>>>(H1, MR1, g1, be1, W2, b2, H2, part2);
  k_reduce<<<10, 256, 0, stream>>>(part2, ROW_BLOCKS, MR2);
  k_out<<<NPTS / 256, 256, 0, stream>>>(H2, MR2, g2, be2, out);
}

// Round 9
// 290.214 us; speedup vs baseline: 1.8607x; 1.0483x over previous
//
#include <hip/hip_runtime.h>
#include <math.h>
#include <float.h>
#include <stdint.h>

#define B_ 4
#define N_ 8192
#define K_ 9
#define NPTS (B_ * N_)           // 32768
#define NROWS (NPTS * K_)        // 294912
#define SPLIT 8
#define CHUNK (N_ / SPLIT)       // 1024
#define NGROUP 32
#define GSIZE (CHUNK / NGROUP)   // 32
#define GSTRIDE 33               // +1 float4 pad -> divergent refill decorrelated

// Distance: EXACT source shape of all passing rounds. Plain mul/add tree —
// identical expression tree in every kernel -> bit-identical distances
// everywhere. DO NOT rewrite with explicit fmaf / reassociation (round 5
// flipped a knife-edge 9th/10th-neighbor decision vs the reference).
__device__ __forceinline__ float dist2f(float4 q, float4 c) {
  float dot = q.x * c.x + q.y * c.y + q.z * c.z;
  return (q.w + c.w) - 2.0f * dot;
}

// ---------------- K0: pack x -> float4 (x,y,z,|x|^2); zero stat accumulators ---
__launch_bounds__(256)
__global__ void k_pack(const float* __restrict__ x, float4* __restrict__ P,
                       double* __restrict__ ACC) {
  if (blockIdx.x == 0 && threadIdx.x < 40) ACC[threadIdx.x] = 0.0;
  int i = blockIdx.x * 256 + threadIdx.x;
  if (i >= NPTS) return;
  float a = x[3 * i], b = x[3 * i + 1], c = x[3 * i + 2];
  P[i] = make_float4(a, b, c, a * a + b * b + c * c);
}

// ---------------- K1: two-level exact top-9 per 1024-chunk, LDS-staged ----------
// All per-lane state in NAMED SCALARS (promote-alloca drops arrays -> scratch).
// launch_bounds(256,4) = 128-reg budget; NGROUP=32 records = 64 scalars.
#define GDECL(G) float gd##G; int gi##G;
#define SCANG(G)                                                           \
  { float bgd = FLT_MAX; int bgi = 0;                                      \
    _Pragma("clang loop unroll(disable)")                                  \
    for (int jj = 0; jj < GSIZE; jj += 4) {                                \
      const float4* cp = CH + (G * GSTRIDE + jj);                          \
      float4 c0 = cp[0], c1 = cp[1], c2 = cp[2], c3 = cp[3];               \
      int j = G * GSIZE + jj;                                              \
      float d0 = dist2f(q, c0), d1 = dist2f(q, c1);                        \
      float d2 = dist2f(q, c2), d3 = dist2f(q, c3);                        \
      if (HS) {                                                            \
        d0 = (j + 0 == nl) ? FLT_MAX : d0;                                 \
        d1 = (j + 1 == nl) ? FLT_MAX : d1;                                 \
        d2 = (j + 2 == nl) ? FLT_MAX : d2;                                 \
        d3 = (j + 3 == nl) ? FLT_MAX : d3;                                 \
      }                                                                    \
      bool l0 = d0 < bgd; bgd = l0 ? d0 : bgd; bgi = l0 ? (j + 0) : bgi;   \
      bool l1 = d1 < bgd; bgd = l1 ? d1 : bgd; bgi = l1 ? (j + 1) : bgi;   \
      bool l2 = d2 < bgd; bgd = l2 ? d2 : bgd; bgi = l2 ? (j + 2) : bgi;   \
      bool l3 = d3 < bgd; bgd = l3 ? d3 : bgd; bgi = l3 ? (j + 3) : bgi;   \
    }                                                                      \
    gd##G = bgd; gi##G = bgi; }
// Group lex-min WITHOUT index compare: groups partition ascending index
// ranges, so strict-< in ascending group order == exact (d, index) order.
#define LM(G)                                                              \
  { bool lt = gd##G < wd;                                                  \
    wd = lt ? gd##G : wd; wi = lt ? gi##G : wi; wg = lt ? G : wg; }
#define WBK(G)                                                             \
  { bool m = (wg == G); gd##G = m ? nd : gd##G; gi##G = m ? ni : gi##G; }

template <bool HS>
__device__ __forceinline__ void knn_chunk(const float4* CH, float4 q, int nl,
                                          int j0, int s, int p,
                                          uint2* __restrict__ PBDI) {
  GDECL(0) GDECL(1) GDECL(2) GDECL(3) GDECL(4) GDECL(5) GDECL(6) GDECL(7)
  GDECL(8) GDECL(9) GDECL(10) GDECL(11) GDECL(12) GDECL(13) GDECL(14) GDECL(15)
  GDECL(16) GDECL(17) GDECL(18) GDECL(19) GDECL(20) GDECL(21) GDECL(22) GDECL(23)
  GDECL(24) GDECL(25) GDECL(26) GDECL(27) GDECL(28) GDECL(29) GDECL(30) GDECL(31)

  SCANG(0) SCANG(1) SCANG(2) SCANG(3) SCANG(4) SCANG(5) SCANG(6) SCANG(7)
  SCANG(8) SCANG(9) SCANG(10) SCANG(11) SCANG(12) SCANG(13) SCANG(14) SCANG(15)
  SCANG(16) SCANG(17) SCANG(18) SCANG(19) SCANG(20) SCANG(21) SCANG(22) SCANG(23)
  SCANG(24) SCANG(25) SCANG(26) SCANG(27) SCANG(28) SCANG(29) SCANG(30) SCANG(31)

#pragma clang loop unroll(disable)
  for (int r = 0; r < K_; ++r) {
    float wd = gd0; int wi = gi0; int wg = 0;
    LM(1) LM(2) LM(3) LM(4) LM(5) LM(6) LM(7)
    LM(8) LM(9) LM(10) LM(11) LM(12) LM(13) LM(14) LM(15)
    LM(16) LM(17) LM(18) LM(19) LM(20) LM(21) LM(22) LM(23)
    LM(24) LM(25) LM(26) LM(27) LM(28) LM(29) LM(30) LM(31)
    uint2 o; o.x = __float_as_uint(wd); o.y = (unsigned)(j0 + wi);
    PBDI[(size_t)(s * K_ + r) * NPTS + p] = o;     // coalesced 8B

    // refill winning group: lex-min over keys strictly > (wd, wi) [local idx]
    int ab = wg * GSTRIDE;
    int jb = wg * GSIZE;
    float nd = FLT_MAX; int ni = 0;
#pragma clang loop unroll(disable)
    for (int jj = 0; jj < GSIZE; jj += 4) {
      const float4* cp = CH + (ab + jj);
      float4 c0 = cp[0], c1 = cp[1], c2 = cp[2], c3 = cp[3];
      int j = jb + jj;
      float d0 = dist2f(q, c0), d1 = dist2f(q, c1);
      float d2 = dist2f(q, c2), d3 = dist2f(q, c3);
      if (HS) {
        d0 = (j + 0 == nl) ? FLT_MAX : d0;
        d1 = (j + 1 == nl) ? FLT_MAX : d1;
        d2 = (j + 2 == nl) ? FLT_MAX : d2;
        d3 = (j + 3 == nl) ? FLT_MAX : d3;
      }
      bool k0 = (d0 > wd) | ((d0 == wd) & ((j + 0) > wi));
      bool k1 = (d1 > wd) | ((d1 == wd) & ((j + 1) > wi));
      bool k2 = (d2 > wd) | ((d2 == wd) & ((j + 2) > wi));
      bool k3 = (d3 > wd) | ((d3 == wd) & ((j + 3) > wi));
      d0 = k0 ? d0 : FLT_MAX;
      d1 = k1 ? d1 : FLT_MAX;
      d2 = k2 ? d2 : FLT_MAX;
      d3 = k3 ? d3 : FLT_MAX;
      bool l0 = d0 < nd; nd = l0 ? d0 : nd; ni = l0 ? (j + 0) : ni;
      bool l1 = d1 < nd; nd = l1 ? d1 : nd; ni = l1 ? (j + 1) : ni;
      bool l2 = d2 < nd; nd = l2 ? d2 : nd; ni = l2 ? (j + 2) : ni;
      bool l3 = d3 < nd; nd = l3 ? d3 : nd; ni = l3 ? (j + 3) : ni;
    }
    WBK(0) WBK(1) WBK(2) WBK(3) WBK(4) WBK(5) WBK(6) WBK(7)
    WBK(8) WBK(9) WBK(10) WBK(11) WBK(12) WBK(13) WBK(14) WBK(15)
    WBK(16) WBK(17) WBK(18) WBK(19) WBK(20) WBK(21) WBK(22) WBK(23)
    WBK(24) WBK(25) WBK(26) WBK(27) WBK(28) WBK(29) WBK(30) WBK(31)
  }
}

__launch_bounds__(256, 4)
__global__ void k_knn2(const float4* __restrict__ P, uint2* __restrict__ PBDI) {
  __shared__ float4 CH[NGROUP * GSTRIDE];   // 16896 B
  int bid = blockIdx.x;
  int pq = bid >> 3;                 // 256-point range [0,128)
  int s = bid & (SPLIT - 1);
  int p = pq * 256 + threadIdx.x;
  int b = p >> 13;                   // block-uniform (256-aligned range)
  int n = p & (N_ - 1);
  const float4* __restrict__ Pb = P + b * N_;
  int j0 = s * CHUNK;

  for (int t = threadIdx.x; t < CHUNK; t += 256) {
    CH[(t >> 5) * GSTRIDE + (t & 31)] = Pb[j0 + t];
  }
  float4 q = Pb[n];
  __syncthreads();

  int n0 = (pq * 256) & (N_ - 1);
  int nl = n - j0;                   // local self index (valid only if HS)
  if (s == (n0 >> 10)) knn_chunk<true >(CH, q, nl, j0, s, p, PBDI);
  else                 knn_chunk<false>(CH, q, nl, j0, s, p, PBDI);
}

// Register-resident sorted top-9 insert (named scalars).
#define LVL(bdv, biv)                                                     \
  { bool lt = cd < (bdv); float td = (bdv); int ti = (biv);               \
    (bdv) = lt ? cd : (bdv); (biv) = lt ? ci : (biv);                     \
    cd = lt ? td : cd; ci = lt ? ti : ci; }
#define INS9ALL()                                                         \
  LVL(b0d, b0i) LVL(b1d, b1i) LVL(b2d, b2i) LVL(b3d, b3i) LVL(b4d, b4i)  \
  LVL(b5d, b5i) LVL(b6d, b6i) LVL(b7d, b7i) LVL(b8d, b8i)
#define TOP9_DECL()                                                       \
  float b0d = FLT_MAX, b1d = FLT_MAX, b2d = FLT_MAX, b3d = FLT_MAX,       \
        b4d = FLT_MAX, b5d = FLT_MAX, b6d = FLT_MAX, b7d = FLT_MAX,       \
        b8d = FLT_MAX;                                                    \
  int b0i = 0, b1i = 0, b2i = 0, b3i = 0, b4i = 0, b5i = 0, b6i = 0,      \
      b7i = 0, b8i = 0;

#define MKREL(T)                                                          \
  float rx##T, ry##T, rz##T, ph##T;                                       \
  { float4 m = Pb[b##T##i];                                               \
    rx##T = m.x - q.x; ry##T = m.y - q.y; rz##T = m.z - q.z;              \
    ph##T = atan2f(ry##T, rx##T); }

#define CE(A, Bv)                                                         \
  { bool lt = ph##Bv < ph##A; float t0;                                   \
    t0 = ph##A; ph##A = lt ? ph##Bv : t0; ph##Bv = lt ? t0 : ph##Bv;      \
    t0 = rx##A; rx##A = lt ? rx##Bv : t0; rx##Bv = lt ? t0 : rx##Bv;      \
    t0 = ry##A; ry##A = lt ? ry##Bv : t0; ry##Bv = lt ? t0 : ry##Bv;      \
    t0 = rz##A; rz##A = lt ? rz##Bv : t0; rz##Bv = lt ? t0 : rz##Bv; }

#define FEAT(T, U)                                                        \
  { float cx = 0.5f * (rx##T + rx##U);                                    \
    float cy = 0.5f * (ry##T + ry##U);                                    \
    float cz = 0.5f * (rz##T + rz##U);                                    \
    float nx = ry##T * rz##U - rz##T * ry##U;                             \
    float ny = rz##T * rx##U - rx##T * rz##U;                             \
    float nz = rx##T * ry##U - ry##T * rx##U;                             \
    float nrm = sqrtf(nx * nx + ny * ny + nz * nz) + 1e-6f;               \
    nx /= nrm; ny /= nrm; nz /= nrm;                                      \
    nx *= sgn; ny *= sgn; nz *= sgn;                                      \
    float pos = (nx * cx + ny * cy + nz * cz) / 1.7320508075688772f;      \
    float fv[7] = {cx, cy, cz, nx, ny, nz, pos};                          \
    _Pragma("unroll")                                                     \
    for (int c = 0; c < 10; ++c) {                                        \
      float h = b1[c];                                                    \
      _Pragma("unroll")                                                   \
      for (int rr = 0; rr < 7; ++rr) h = fmaf(fv[rr], W1[rr * 10 + c], h);\
      H1[(size_t)c * NROWS + (size_t)T * NPTS + p] = h;                   \
      double hd = (double)h;                                              \
      sum[c] += hd; ss[c] += hd * hd;                                     \
    } }

// ---------------- K2: merge 8 sorted lists, phi-sort, features, W1, stats ------
__launch_bounds__(256)
__global__ void k_merge(const float4* __restrict__ P, const uint2* __restrict__ PBDI,
                        const float* __restrict__ W1, const float* __restrict__ b1,
                        float* __restrict__ H1, double* __restrict__ ACC1) {
  int p = blockIdx.x * 256 + threadIdx.x;
  int b = p >> 13;
  int n = p & (N_ - 1);
  const float4* __restrict__ Pb = P + b * N_;
  float4 q = Pb[n];

  // ascending (chunk, rank) order + strict-< insertion = exact lex (d, index)
  // top-9 with top_k tie-breaking (chunks are ascending index ranges).
  TOP9_DECL();
#pragma unroll 8
  for (int t = 0; t < SPLIT * K_; ++t) {
    uint2 v = PBDI[(size_t)t * NPTS + p];       // coalesced 8B
    float cd = __uint_as_float(v.x);
    int ci = (int)v.y;
    INS9ALL();
  }

  MKREL(0) MKREL(1) MKREL(2) MKREL(3) MKREL(4)
  MKREL(5) MKREL(6) MKREL(7) MKREL(8)

  // stable insertion-sort network ascending by phi (36 strict-< CEs)
  CE(0,1)
  CE(1,2) CE(0,1)
  CE(2,3) CE(1,2) CE(0,1)
  CE(3,4) CE(2,3) CE(1,2) CE(0,1)
  CE(4,5) CE(3,4) CE(2,3) CE(1,2) CE(0,1)
  CE(5,6) CE(4,5) CE(3,4) CE(2,3) CE(1,2) CE(0,1)
  CE(6,7) CE(5,6) CE(4,5) CE(3,4) CE(2,3) CE(1,2) CE(0,1)
  CE(7,8) CE(6,7) CE(5,6) CE(4,5) CE(3,4) CE(2,3) CE(1,2) CE(0,1)

  // sign from triangle 0's NORMALIZED nx (reference semantics)
  float sgn;
  { float nx0 = ry0 * rz1 - rz0 * ry1;
    float ny0 = rz0 * rx1 - rx0 * rz1;
    float nz0 = rx0 * ry1 - ry0 * rx1;
    float nrm0 = sqrtf(nx0 * nx0 + ny0 * ny0 + nz0 * nz0) + 1e-6f;
    sgn = ((nx0 / nrm0) > 0.0f) ? 1.0f : -1.0f; }

  double sum[10], ss[10];
#pragma unroll
  for (int c = 0; c < 10; ++c) { sum[c] = 0.0; ss[c] = 0.0; }

  FEAT(0,1) FEAT(1,2) FEAT(2,3) FEAT(3,4) FEAT(4,5)
  FEAT(5,6) FEAT(6,7) FEAT(7,8) FEAT(8,0)

  __shared__ double sred[4][20];
  int lane = threadIdx.x & 63, wv = threadIdx.x >> 6;
#pragma unroll
  for (int c = 0; c < 10; ++c) {
    double a = sum[c];
#pragma unroll
    for (int off = 32; off > 0; off >>= 1) a += __shfl_down(a, off);
    if (lane == 0) sred[wv][c] = a;
    double qq = ss[c];
#pragma unroll
    for (int off = 32; off > 0; off >>= 1) qq += __shfl_down(qq, off);
    if (lane == 0) sred[wv][10 + c] = qq;
  }
  __syncthreads();
  if (threadIdx.x < 20) {
    atomicAdd(&ACC1[threadIdx.x],
              sred[0][threadIdx.x] + sred[1][threadIdx.x] +
              sred[2][threadIdx.x] + sred[3][threadIdx.x]);
  }
}

// ---------------- K3: bn1(from ACC1) + relu + @W2+b2 -> H2 + stats->ACC2 --------
__launch_bounds__(512)
__global__ void k_mlp2(const float* __restrict__ H1, const double* __restrict__ ACC1,
                       const float* __restrict__ g1, const float* __restrict__ be1,
                       const float* __restrict__ W2, const float* __restrict__ b2,
                       float* __restrict__ H2, double* __restrict__ ACC2) {
  __shared__ float MR[20];
  if (threadIdx.x < 10) {
    double mu = ACC1[threadIdx.x] / (double)NROWS;
    double var = ACC1[10 + threadIdx.x] / (double)NROWS - mu * mu;
    MR[threadIdx.x] = (float)mu;
    MR[10 + threadIdx.x] = (float)(1.0 / sqrt(var + 1e-5));
  }
  __syncthreads();

  int r = blockIdx.x * 512 + threadIdx.x;
  float v[10];
#pragma unroll
  for (int c = 0; c < 10; ++c) {
    float h = H1[(size_t)c * NROWS + r];
    float z = g1[c] * (h - MR[c]) * MR[10 + c] + be1[c];
    v[c] = z > 0.0f ? z : 0.0f;
  }
  float o[10];
#pragma unroll
  for (int c = 0; c < 10; ++c) {
    float h = b2[c];
#pragma unroll
    for (int t = 0; t < 10; ++t) h = fmaf(v[t], W2[t * 10 + c], h);
    o[c] = h;
    H2[(size_t)c * NROWS + r] = h;
  }

  __shared__ double sred[8][20];
  int lane = threadIdx.x & 63, wv = threadIdx.x >> 6;
#pragma unroll
  for (int c = 0; c < 10; ++c) {
    double a = (double)o[c];
#pragma unroll
    for (int off = 32; off > 0; off >>= 1) a += __shfl_down(a, off);
    if (lane == 0) sred[wv][c] = a;
    double qq = (double)o[c] * (double)o[c];
#pragma unroll
    for (int off = 32; off > 0; off >>= 1) qq += __shfl_down(qq, off);
    if (lane == 0) sred[wv][10 + c] = qq;
  }
  __syncthreads();
  if (threadIdx.x < 20) {
    double t = 0.0;
#pragma unroll
    for (int w = 0; w < 8; ++w) t += sred[w][threadIdx.x];
    atomicAdd(&ACC2[threadIdx.x], t);
  }
}

// ---------------- K4: bn2(from ACC2) + relu + max over k -> out -----------------
__launch_bounds__(256)
__global__ void k_out(const float* __restrict__ H2, const double* __restrict__ ACC2,
                      const float* __restrict__ g2, const float* __restrict__ be2,
                      float* __restrict__ out) {
  __shared__ float MR[20];
  if (threadIdx.x < 10) {
    double mu = ACC2[threadIdx.x] / (double)NROWS;
    double var = ACC2[10 + threadIdx.x] / (double)NROWS - mu * mu;
    MR[threadIdx.x] = (float)mu;
    MR[10 + threadIdx.x] = (float)(1.0 / sqrt(var + 1e-5));
  }
  __syncthreads();

  int p = blockIdx.x * 256 + threadIdx.x;
#pragma unroll
  for (int c = 0; c < 10; ++c) {
    float m = -FLT_MAX;
#pragma unroll
    for (int j = 0; j < K_; ++j) {
      float h = H2[(size_t)c * NROWS + j * NPTS + p];   // coalesced
      float z = g2[c] * (h - MR[c]) * MR[10 + c] + be2[c];
      z = z > 0.0f ? z : 0.0f;
      m = fmaxf(m, z);
    }
    out[(size_t)p * 10 + c] = m;
  }
}

extern "C" void kernel_launch(void* const* d_in, const int* in_sizes, int n_in,
                              void* d_out, int out_size, void* d_ws, size_t ws_size,
                              hipStream_t stream) {
  (void)in_sizes; (void)n_in; (void)out_size; (void)ws_size;
  const float* x  = (const float*)d_in[0];
  const float* W1 = (const float*)d_in[1];
  const float* b1 = (const float*)d_in[2];
  const float* g1 = (const float*)d_in[3];
  const float* be1= (const float*)d_in[4];
  const float* W2 = (const float*)d_in[5];
  const float* b2 = (const float*)d_in[6];
  const float* g2 = (const float*)d_in[7];
  const float* be2= (const float*)d_in[8];
  float* out = (float*)d_out;

  char* base = (char*)d_ws;
  float4* P    = (float4*)base;                                  // 512 KB
  uint2*  PBDI = (uint2*)(base + (size_t)NPTS * 16);             // 72 slices, 18.9 MB
  float*  H1   = (float*)((char*)PBDI + (size_t)SPLIT * K_ * NPTS * 8); // 11.8 MB
  double* ACC  = (double*)(H1 + (size_t)10 * NROWS);             // 40 doubles
  double* ACC1 = ACC;
  double* ACC2 = ACC + 20;
  // H2 aliases PBDI (dead after k_merge)
  float*  H2 = (float*)PBDI;                                     // 11.8 of 18.9 MB

  k_pack<<<NPTS / 256, 256, 0, stream>>>(x, P, ACC);
  k_knn2<<<(NPTS / 256) * SPLIT, 256, 0, stream>>>(P, PBDI);
  k_merge<<<NPTS / 256, 256, 0, stream>>>(P, PBDI, W1, b1, H1, ACC1);
  k_mlp2<<<NROWS / 512, 512, 0, stream>>>(H1, ACC1, g1, be1, W2, b2, H2, ACC2);
  k_out<<<NPTS / 256, 256, 0, stream>>>(H2, ACC2, g2, be2, out);
}

// Round 10
// 288.064 us; speedup vs baseline: 1.8746x; 1.0075x over previous
//
#include <hip/hip_runtime.h>
#include <math.h>
#include <float.h>
#include <stdint.h>

#define B_ 4
#define N_ 8192
#define K_ 9
#define NPTS (B_ * N_)           // 32768
#define NROWS (NPTS * K_)        // 294912
#define SPLIT 16
#define CHUNK (N_ / SPLIT)       // 512
#define NGROUP 16
#define GSIZE (CHUNK / NGROUP)   // 32
#define GSTRIDE 33               // +1 float4 pad
#define MBLK 128                 // tail blocks (<=256 CUs -> co-resident)
#define RPB (NROWS / MBLK)       // 2304 rows per tail block

// Distance: EXACT source shape of all passing rounds. Plain mul/add tree —
// identical expression tree in every kernel -> bit-identical distances
// everywhere. DO NOT rewrite with explicit fmaf / reassociation (round 5
// flipped a knife-edge 9th/10th-neighbor decision vs the reference).
__device__ __forceinline__ float dist2f(float4 q, float4 c) {
  float dot = q.x * c.x + q.y * c.y + q.z * c.z;
  return (q.w + c.w) - 2.0f * dot;
}

// ---------------- K1: two-level exact top-9 per 512-chunk, LDS-staged ----------
// Named scalars for all per-lane state. launch_bounds(256,6) = 85-reg budget
// (64-reg cap spills this state — round 7; 128-reg cap wastes occupancy).
#define GDECL(G) float gd##G; int gi##G;
#define SCANG(G)                                                           \
  { float bgd = FLT_MAX; int bgi = 0;                                      \
    _Pragma("clang loop unroll(disable)")                                  \
    for (int jj = 0; jj < GSIZE; jj += 4) {                                \
      const float4* cp = CH + (G * GSTRIDE + jj);                          \
      float4 c0 = cp[0], c1 = cp[1], c2 = cp[2], c3 = cp[3];               \
      int j = G * GSIZE + jj;                                              \
      float d0 = dist2f(q, c0), d1 = dist2f(q, c1);                        \
      float d2 = dist2f(q, c2), d3 = dist2f(q, c3);                        \
      if (HS) {                                                            \
        d0 = (j + 0 == nl) ? FLT_MAX : d0;                                 \
        d1 = (j + 1 == nl) ? FLT_MAX : d1;                                 \
        d2 = (j + 2 == nl) ? FLT_MAX : d2;                                 \
        d3 = (j + 3 == nl) ? FLT_MAX : d3;                                 \
      }                                                                    \
      bool l0 = d0 < bgd; bgd = l0 ? d0 : bgd; bgi = l0 ? (j + 0) : bgi;   \
      bool l1 = d1 < bgd; bgd = l1 ? d1 : bgd; bgi = l1 ? (j + 1) : bgi;   \
      bool l2 = d2 < bgd; bgd = l2 ? d2 : bgd; bgi = l2 ? (j + 2) : bgi;   \
      bool l3 = d3 < bgd; bgd = l3 ? d3 : bgd; bgi = l3 ? (j + 3) : bgi;   \
    }                                                                      \
    gd##G = bgd; gi##G = bgi; }
// Group lex-min WITHOUT index compare: groups partition ascending index
// ranges, so strict-< in ascending group order == exact (d, index) order.
#define LM(G)                                                              \
  { bool lt = gd##G < wd;                                                  \
    wd = lt ? gd##G : wd; wi = lt ? gi##G : wi; wg = lt ? G : wg; }
#define WBK(G)                                                             \
  { bool m = (wg == G); gd##G = m ? nd : gd##G; gi##G = m ? ni : gi##G; }

template <bool HS>
__device__ __forceinline__ void knn_chunk(const float4* CH, float4 q, int nl,
                                          int j0, int s, int p,
                                          uint2* __restrict__ PBDI) {
  GDECL(0) GDECL(1) GDECL(2) GDECL(3) GDECL(4) GDECL(5) GDECL(6) GDECL(7)
  GDECL(8) GDECL(9) GDECL(10) GDECL(11) GDECL(12) GDECL(13) GDECL(14) GDECL(15)

  SCANG(0) SCANG(1) SCANG(2) SCANG(3) SCANG(4) SCANG(5) SCANG(6) SCANG(7)
  SCANG(8) SCANG(9) SCANG(10) SCANG(11) SCANG(12) SCANG(13) SCANG(14) SCANG(15)

#pragma clang loop unroll(disable)
  for (int r = 0; r < K_; ++r) {
    float wd = gd0; int wi = gi0; int wg = 0;
    LM(1) LM(2) LM(3) LM(4) LM(5) LM(6) LM(7)
    LM(8) LM(9) LM(10) LM(11) LM(12) LM(13) LM(14) LM(15)
    uint2 o; o.x = __float_as_uint(wd); o.y = (unsigned)(j0 + wi);
    PBDI[(size_t)(s * K_ + r) * NPTS + p] = o;     // coalesced 8B

    // refill winning group: lex-min over keys strictly > (wd, wi) [local idx]
    int ab = wg * GSTRIDE;
    int jb = wg * GSIZE;
    float nd = FLT_MAX; int ni = 0;
#pragma clang loop unroll(disable)
    for (int jj = 0; jj < GSIZE; jj += 4) {
      const float4* cp = CH + (ab + jj);
      float4 c0 = cp[0], c1 = cp[1], c2 = cp[2], c3 = cp[3];
      int j = jb + jj;
      float d0 = dist2f(q, c0), d1 = dist2f(q, c1);
      float d2 = dist2f(q, c2), d3 = dist2f(q, c3);
      if (HS) {
        d0 = (j + 0 == nl) ? FLT_MAX : d0;
        d1 = (j + 1 == nl) ? FLT_MAX : d1;
        d2 = (j + 2 == nl) ? FLT_MAX : d2;
        d3 = (j + 3 == nl) ? FLT_MAX : d3;
      }
      bool k0 = (d0 > wd) | ((d0 == wd) & ((j + 0) > wi));
      bool k1 = (d1 > wd) | ((d1 == wd) & ((j + 1) > wi));
      bool k2 = (d2 > wd) | ((d2 == wd) & ((j + 2) > wi));
      bool k3 = (d3 > wd) | ((d3 == wd) & ((j + 3) > wi));
      d0 = k0 ? d0 : FLT_MAX;
      d1 = k1 ? d1 : FLT_MAX;
      d2 = k2 ? d2 : FLT_MAX;
      d3 = k3 ? d3 : FLT_MAX;
      bool l0 = d0 < nd; nd = l0 ? d0 : nd; ni = l0 ? (j + 0) : ni;
      bool l1 = d1 < nd; nd = l1 ? d1 : nd; ni = l1 ? (j + 1) : ni;
      bool l2 = d2 < nd; nd = l2 ? d2 : nd; ni = l2 ? (j + 2) : ni;
      bool l3 = d3 < nd; nd = l3 ? d3 : nd; ni = l3 ? (j + 3) : ni;
    }
    WBK(0) WBK(1) WBK(2) WBK(3) WBK(4) WBK(5) WBK(6) WBK(7)
    WBK(8) WBK(9) WBK(10) WBK(11) WBK(12) WBK(13) WBK(14) WBK(15)
  }
}

__launch_bounds__(256, 6)
__global__ void k_knn(const float* __restrict__ x, uint2* __restrict__ PBDI) {
  __shared__ float4 CH[NGROUP * GSTRIDE];   // 8448 B
  int bid = blockIdx.x;
  int pq = bid >> 4;                 // 256-point range [0,128)
  int s = bid & (SPLIT - 1);
  int p = pq * 256 + threadIdx.x;
  int b = p >> 13;                   // block-uniform (256-aligned range)
  int n = p & (N_ - 1);
  int bO = b * N_;
  int j0 = s * CHUNK;

  // stage chunk -> LDS from x; w = a*a+b*b+c*c (EXACT expression everywhere)
  for (int t = threadIdx.x; t < CHUNK; t += 256) {
    const float* xp = x + 3 * (size_t)(bO + j0 + t);
    float a = xp[0], bb = xp[1], cc = xp[2];
    CH[(t >> 5) * GSTRIDE + (t & 31)] = make_float4(a, bb, cc, a * a + bb * bb + cc * cc);
  }
  const float* xq = x + 3 * (size_t)p;
  float qa = xq[0], qb = xq[1], qc = xq[2];
  float4 q = make_float4(qa, qb, qc, qa * qa + qb * qb + qc * qc);
  __syncthreads();

  int n0 = (pq * 256) & (N_ - 1);    // block-uniform
  int nl = n - j0;                   // local self index (valid only if HS)
  if (s == (n0 >> 9)) knn_chunk<true >(CH, q, nl, j0, s, p, PBDI);
  else                knn_chunk<false>(CH, q, nl, j0, s, p, PBDI);
}

// ---------------- K2: fused tail (merge+feat+W1 | bn1+W2 | bn2+max) ------------
#define LVL(bdv, biv)                                                     \
  { bool lt = cd < (bdv); float td = (bdv); int ti = (biv);               \
    (bdv) = lt ? cd : (bdv); (biv) = lt ? ci : (biv);                     \
    cd = lt ? td : cd; ci = lt ? ti : ci; }
#define INS9ALL()                                                         \
  LVL(b0d, b0i) LVL(b1d, b1i) LVL(b2d, b2i) LVL(b3d, b3i) LVL(b4d, b4i)  \
  LVL(b5d, b5i) LVL(b6d, b6i) LVL(b7d, b7i) LVL(b8d, b8i)
#define TOP9_DECL()                                                       \
  float b0d = FLT_MAX, b1d = FLT_MAX, b2d = FLT_MAX, b3d = FLT_MAX,       \
        b4d = FLT_MAX, b5d = FLT_MAX, b6d = FLT_MAX, b7d = FLT_MAX,       \
        b8d = FLT_MAX;                                                    \
  int b0i = 0, b1i = 0, b2i = 0, b3i = 0, b4i = 0, b5i = 0, b6i = 0,      \
      b7i = 0, b8i = 0;

#define MKREL(T)                                                          \
  float rx##T, ry##T, rz##T, ph##T;                                       \
  { const float* mp = x + 3 * (size_t)(bO + b##T##i);                     \
    rx##T = mp[0] - qa; ry##T = mp[1] - qb; rz##T = mp[2] - qc;           \
    ph##T = atan2f(ry##T, rx##T); }

#define CE(A, Bv)                                                         \
  { bool lt = ph##Bv < ph##A; float t0;                                   \
    t0 = ph##A; ph##A = lt ? ph##Bv : t0; ph##Bv = lt ? t0 : ph##Bv;      \
    t0 = rx##A; rx##A = lt ? rx##Bv : t0; rx##Bv = lt ? t0 : rx##Bv;      \
    t0 = ry##A; ry##A = lt ? ry##Bv : t0; ry##Bv = lt ? t0 : ry##Bv;      \
    t0 = rz##A; rz##A = lt ? rz##Bv : t0; rz##Bv = lt ? t0 : rz##Bv; }

#define FEAT(T, U)                                                        \
  { float cx = 0.5f * (rx##T + rx##U);                                    \
    float cy = 0.5f * (ry##T + ry##U);                                    \
    float cz = 0.5f * (rz##T + rz##U);                                    \
    float nx = ry##T * rz##U - rz##T * ry##U;                             \
    float ny = rz##T * rx##U - rx##T * rz##U;                             \
    float nz = rx##T * ry##U - ry##T * rx##U;                             \
    float nrm = sqrtf(nx * nx + ny * ny + nz * nz) + 1e-6f;               \
    nx /= nrm; ny /= nrm; nz /= nrm;                                      \
    nx *= sgn; ny *= sgn; nz *= sgn;                                      \
    float pos = (nx * cx + ny * cy + nz * cz) / 1.7320508075688772f;      \
    float fv[7] = {cx, cy, cz, nx, ny, nz, pos};                          \
    _Pragma("unroll")                                                     \
    for (int c = 0; c < 10; ++c) {                                        \
      float h = b1[c];                                                    \
      _Pragma("unroll")                                                   \
      for (int rr = 0; rr < 7; ++rr) h = fmaf(fv[rr], W1[rr * 10 + c], h);\
      H1[(size_t)c * NROWS + (size_t)T * NPTS + p] = h;                   \
      double hd = (double)h;                                              \
      sum[c] += hd; ss[c] += hd * hd;                                     \
    } }

// Device-scope spin barrier. MBLK=128 blocks <= 256 CUs -> all co-resident,
// no deadlock. Release on inc, acquire on poll (agent scope) per G16.
__device__ __forceinline__ void gridbar(int* ctr, int target) {
  __syncthreads();
  if (threadIdx.x == 0) {
    __hip_atomic_fetch_add(ctr, 1, __ATOMIC_RELEASE, __HIP_MEMORY_SCOPE_AGENT);
    while (__hip_atomic_load(ctr, __ATOMIC_ACQUIRE, __HIP_MEMORY_SCOPE_AGENT) < target) {
      __builtin_amdgcn_s_sleep(8);
    }
  }
  __syncthreads();
}

__launch_bounds__(256)
__global__ void k_tail(const float* __restrict__ x, const uint2* __restrict__ PBDI,
                       const float* __restrict__ W1, const float* __restrict__ b1,
                       const float* __restrict__ g1, const float* __restrict__ be1,
                       const float* __restrict__ W2, const float* __restrict__ b2,
                       const float* __restrict__ g2, const float* __restrict__ be2,
                       float* __restrict__ H1, float* __restrict__ H2,
                       double* __restrict__ ACC, int* __restrict__ CTR,
                       float* __restrict__ out) {
  double* ACC1 = ACC;
  double* ACC2 = ACC + 20;
  __shared__ double sred[4][20];
  __shared__ float MR[20];
  int lane = threadIdx.x & 63, wv = threadIdx.x >> 6;
  int p = blockIdx.x * 256 + threadIdx.x;
  int b = p >> 13;
  int bO = b * N_;

  // ---- phase 1: merge 144 sorted entries, phi-sort, features, W1, stats ----
  {
    const float* xq = x + 3 * (size_t)p;
    float qa = xq[0], qb = xq[1], qc = xq[2];

    TOP9_DECL();
#pragma unroll 8
    for (int t = 0; t < SPLIT * K_; ++t) {
      uint2 v = PBDI[(size_t)t * NPTS + p];       // coalesced 8B
      float cd = __uint_as_float(v.x);
      int ci = (int)v.y;
      INS9ALL();
    }

    MKREL(0) MKREL(1) MKREL(2) MKREL(3) MKREL(4)
    MKREL(5) MKREL(6) MKREL(7) MKREL(8)

    CE(0,1)
    CE(1,2) CE(0,1)
    CE(2,3) CE(1,2) CE(0,1)
    CE(3,4) CE(2,3) CE(1,2) CE(0,1)
    CE(4,5) CE(3,4) CE(2,3) CE(1,2) CE(0,1)
    CE(5,6) CE(4,5) CE(3,4) CE(2,3) CE(1,2) CE(0,1)
    CE(6,7) CE(5,6) CE(4,5) CE(3,4) CE(2,3) CE(1,2) CE(0,1)
    CE(7,8) CE(6,7) CE(5,6) CE(4,5) CE(3,4) CE(2,3) CE(1,2) CE(0,1)

    float sgn;
    { float nx0 = ry0 * rz1 - rz0 * ry1;
      float ny0 = rz0 * rx1 - rx0 * rz1;
      float nz0 = rx0 * ry1 - ry0 * rx1;
      float nrm0 = sqrtf(nx0 * nx0 + ny0 * ny0 + nz0 * nz0) + 1e-6f;
      sgn = ((nx0 / nrm0) > 0.0f) ? 1.0f : -1.0f; }

    double sum[10], ss[10];
#pragma unroll
    for (int c = 0; c < 10; ++c) { sum[c] = 0.0; ss[c] = 0.0; }

    FEAT(0,1) FEAT(1,2) FEAT(2,3) FEAT(3,4) FEAT(4,5)
    FEAT(5,6) FEAT(6,7) FEAT(7,8) FEAT(8,0)

#pragma unroll
    for (int c = 0; c < 10; ++c) {
      double a = sum[c];
#pragma unroll
      for (int off = 32; off > 0; off >>= 1) a += __shfl_down(a, off);
      if (lane == 0) sred[wv][c] = a;
      double qq = ss[c];
#pragma unroll
      for (int off = 32; off > 0; off >>= 1) qq += __shfl_down(qq, off);
      if (lane == 0) sred[wv][10 + c] = qq;
    }
    __syncthreads();
    if (threadIdx.x < 20) {
      atomicAdd(&ACC1[threadIdx.x],
                sred[0][threadIdx.x] + sred[1][threadIdx.x] +
                sred[2][threadIdx.x] + sred[3][threadIdx.x]);
    }
  }

  gridbar(CTR, MBLK);

  // ---- phase 2: bn1 + relu + @W2+b2 -> H2 + stats2 ----
  {
    if (threadIdx.x < 10) {
      double mu = ACC1[threadIdx.x] / (double)NROWS;
      double var = ACC1[10 + threadIdx.x] / (double)NROWS - mu * mu;
      MR[threadIdx.x] = (float)mu;
      MR[10 + threadIdx.x] = (float)(1.0 / sqrt(var + 1e-5));
    }
    __syncthreads();

    double sum[10], ss[10];
#pragma unroll
    for (int c = 0; c < 10; ++c) { sum[c] = 0.0; ss[c] = 0.0; }

#pragma clang loop unroll(disable)
    for (int k = 0; k < K_; ++k) {
      int r = blockIdx.x * RPB + k * 256 + threadIdx.x;
      float v[10];
#pragma unroll
      for (int c = 0; c < 10; ++c) {
        float h = H1[(size_t)c * NROWS + r];
        float z = g1[c] * (h - MR[c]) * MR[10 + c] + be1[c];
        v[c] = z > 0.0f ? z : 0.0f;
      }
#pragma unroll
      for (int c = 0; c < 10; ++c) {
        float h = b2[c];
#pragma unroll
        for (int t = 0; t < 10; ++t) h = fmaf(v[t], W2[t * 10 + c], h);
        H2[(size_t)c * NROWS + r] = h;
        double hd = (double)h;
        sum[c] += hd; ss[c] += hd * hd;
      }
    }

    __syncthreads();   // sred reuse
#pragma unroll
    for (int c = 0; c < 10; ++c) {
      double a = sum[c];
#pragma unroll
      for (int off = 32; off > 0; off >>= 1) a += __shfl_down(a, off);
      if (lane == 0) sred[wv][c] = a;
      double qq = ss[c];
#pragma unroll
      for (int off = 32; off > 0; off >>= 1) qq += __shfl_down(qq, off);
      if (lane == 0) sred[wv][10 + c] = qq;
    }
    __syncthreads();
    if (threadIdx.x < 20) {
      atomicAdd(&ACC2[threadIdx.x],
                sred[0][threadIdx.x] + sred[1][threadIdx.x] +
                sred[2][threadIdx.x] + sred[3][threadIdx.x]);
    }
  }

  gridbar(CTR, 2 * MBLK);

  // ---- phase 3: bn2 + relu + max over k -> out ----
  {
    if (threadIdx.x < 10) {
      double mu = ACC2[threadIdx.x] / (double)NROWS;
      double var = ACC2[10 + threadIdx.x] / (double)NROWS - mu * mu;
      MR[threadIdx.x] = (float)mu;
      MR[10 + threadIdx.x] = (float)(1.0 / sqrt(var + 1e-5));
    }
    __syncthreads();

#pragma unroll
    for (int c = 0; c < 10; ++c) {
      float m = -FLT_MAX;
#pragma unroll
      for (int j = 0; j < K_; ++j) {
        float h = H2[(size_t)c * NROWS + j * NPTS + p];   // coalesced
        float z = g2[c] * (h - MR[c]) * MR[10 + c] + be2[c];
        z = z > 0.0f ? z : 0.0f;
        m = fmaxf(m, z);
      }
      out[(size_t)p * 10 + c] = m;
    }
  }
}

extern "C" void kernel_launch(void* const* d_in, const int* in_sizes, int n_in,
                              void* d_out, int out_size, void* d_ws, size_t ws_size,
                              hipStream_t stream) {
  (void)in_sizes; (void)n_in; (void)out_size; (void)ws_size;
  const float* x  = (const float*)d_in[0];
  const float* W1 = (const float*)d_in[1];
  const float* b1 = (const float*)d_in[2];
  const float* g1 = (const float*)d_in[3];
  const float* be1= (const float*)d_in[4];
  const float* W2 = (const float*)d_in[5];
  const float* b2 = (const float*)d_in[6];
  const float* g2 = (const float*)d_in[7];
  const float* be2= (const float*)d_in[8];
  float* out = (float*)d_out;

  char* base = (char*)d_ws;
  uint2*  PBDI = (uint2*)base;                          // 144 slices, 36.9 MB
  // H1 aliases PBDI slices [0,48): k_tail phase1 reads ALL its PBDI column
  // before writing H1 at the same column; columns disjoint across threads.
  float*  H1 = (float*)base;                            // 11.8 MB
  float*  H2 = (float*)(base + (size_t)48 * NPTS * 8);  // slices [48,96)
  char*   sync = base + (size_t)SPLIT * K_ * NPTS * 8;  // after PBDI
  double* ACC = (double*)sync;                          // 40 doubles
  int*    CTR = (int*)(sync + 40 * sizeof(double));

  hipMemsetAsync(sync, 0, 40 * sizeof(double) + sizeof(int), stream);
  k_knn<<<(NPTS / 256) * SPLIT, 256, 0, stream>>>(x, PBDI);
  k_tail<<<MBLK, 256, 0, stream>>>(x, PBDI, W1, b1, g1, be1, W2, b2, g2, be2,
                                   H1, H2, ACC, CTR, out);
}